// Round 1
// baseline (1735.269 us; speedup 1.0000x reference)
//
#include <hip/hip_runtime.h>
#include <hip/hip_bf16.h>
#include <math.h>

// Mamba block fwd, fp32 baseline.
// B=4, L=1024, d_model=768, d_inner=1536, dt_rank=48, d_state=16, d_conv=4.

#define BB 4
#define LL 1024
#define DMODEL 768
#define DSTATE 16
#define DINNER 1536
#define DTRANK 48
#define NROWS (BB*LL)   // 4096
#define EPSF 1e-5f

// ---------------- RMSNorm: one wave per row (768 cols = 64 lanes * 3 float4)
__global__ __launch_bounds__(256) void rmsnorm_kernel(const float* __restrict__ x,
                                                      const float* __restrict__ w,
                                                      float* __restrict__ out) {
    int wave = threadIdx.x >> 6;
    int lane = threadIdx.x & 63;
    int row  = blockIdx.x * 4 + wave;
    const float4* xr = reinterpret_cast<const float4*>(x + (size_t)row * DMODEL);
    const float4* wr = reinterpret_cast<const float4*>(w);
    float4 v[3];
    float ss = 0.f;
#pragma unroll
    for (int i = 0; i < 3; i++) {
        v[i] = xr[lane + i * 64];
        ss += v[i].x*v[i].x + v[i].y*v[i].y + v[i].z*v[i].z + v[i].w*v[i].w;
    }
#pragma unroll
    for (int m = 1; m < 64; m <<= 1) ss += __shfl_xor(ss, m);
    float scale = rsqrtf(ss * (1.0f / DMODEL) + EPSF);
    float4* orow = reinterpret_cast<float4*>(out + (size_t)row * DMODEL);
#pragma unroll
    for (int i = 0; i < 3; i++) {
        float4 wv = wr[lane + i * 64];
        float4 o;
        o.x = v[i].x * scale * wv.x;
        o.y = v[i].y * scale * wv.y;
        o.z = v[i].z * scale * wv.z;
        o.w = v[i].w * scale * wv.w;
        orow[lane + i * 64] = o;
    }
}

// ---------------- Generic tiled fp32 GEMM: C[M][N] = A[M][K] * W[N][K]^T (+Res)
// 64x64 tile, 256 threads, 4x4 per thread, TK=16, float4 loads/writes.
// M must be multiple of 64 and K multiple of 16 (true for all call sites).
__global__ __launch_bounds__(256) void gemm_bt(const float* __restrict__ A, int lda,
                                               const float* __restrict__ W, int ldw,
                                               const float* __restrict__ Res,
                                               float* __restrict__ C, int ldc,
                                               int M, int N, int K) {
    __shared__ float As[16][68];   // [k][m], row stride 68 floats = 16B-aligned
    __shared__ float Ws[16][68];   // [k][n]
    int tid = threadIdx.x;
    int tx = tid & 15, ty = tid >> 4;
    int m0 = blockIdx.y * 64, n0 = blockIdx.x * 64;
    int lrow = tid >> 2;          // 0..63
    int lk   = (tid & 3) * 4;     // 0,4,8,12
    int arow = m0 + lrow;
    int wrow = n0 + lrow;
    bool wvalid = (wrow < N);
    float acc[4][4] = {};

    for (int k0 = 0; k0 < K; k0 += 16) {
        float4 av = *reinterpret_cast<const float4*>(A + (size_t)arow * lda + k0 + lk);
        float4 wv = wvalid ? *reinterpret_cast<const float4*>(W + (size_t)wrow * ldw + k0 + lk)
                           : make_float4(0.f, 0.f, 0.f, 0.f);
        __syncthreads();
        As[lk+0][lrow] = av.x; As[lk+1][lrow] = av.y; As[lk+2][lrow] = av.z; As[lk+3][lrow] = av.w;
        Ws[lk+0][lrow] = wv.x; Ws[lk+1][lrow] = wv.y; Ws[lk+2][lrow] = wv.z; Ws[lk+3][lrow] = wv.w;
        __syncthreads();
#pragma unroll
        for (int kk = 0; kk < 16; kk++) {
            float4 a = *reinterpret_cast<const float4*>(&As[kk][ty * 4]);
            float4 w = *reinterpret_cast<const float4*>(&Ws[kk][tx * 4]);
            acc[0][0] += a.x * w.x; acc[0][1] += a.x * w.y; acc[0][2] += a.x * w.z; acc[0][3] += a.x * w.w;
            acc[1][0] += a.y * w.x; acc[1][1] += a.y * w.y; acc[1][2] += a.y * w.z; acc[1][3] += a.y * w.w;
            acc[2][0] += a.z * w.x; acc[2][1] += a.z * w.y; acc[2][2] += a.z * w.z; acc[2][3] += a.z * w.w;
            acc[3][0] += a.w * w.x; acc[3][1] += a.w * w.y; acc[3][2] += a.w * w.z; acc[3][3] += a.w * w.w;
        }
    }

#pragma unroll
    for (int i = 0; i < 4; i++) {
        int row = m0 + ty * 4 + i;
        int col = n0 + tx * 4;
        if (col < N) {
            float4 o = make_float4(acc[i][0], acc[i][1], acc[i][2], acc[i][3]);
            if (Res) {
                float4 r = *reinterpret_cast<const float4*>(Res + (size_t)row * ldc + col);
                o.x += r.x; o.y += r.y; o.z += r.z; o.w += r.w;
            }
            *reinterpret_cast<float4*>(C + (size_t)row * ldc + col) = o;
        }
    }
}

// ---------------- causal depthwise conv (k=4) + bias + SiLU
// reads x = xz[:, 0:1536] (ld 3072), writes xconv (ld 1536)
__global__ __launch_bounds__(256) void conv_silu_kernel(const float* __restrict__ xz,
                                                        const float* __restrict__ cw,
                                                        const float* __restrict__ cb,
                                                        float* __restrict__ out) {
    int idx = blockIdx.x * 256 + threadIdx.x;   // < 4096*1536
    int d  = idx % DINNER;
    int ml = idx / DINNER;    // b*1024 + l
    int l  = ml % LL;
    float acc = cb[d];
#pragma unroll
    for (int i = 0; i < 4; i++) {
        int li = l - 3 + i;
        if (li >= 0) acc += xz[(size_t)(ml - 3 + i) * 3072 + d] * cw[d * 4 + i];
    }
    out[idx] = acc / (1.f + expf(-acc));   // SiLU
}

// ---------------- selective scan, thread per (b,d,n); 16-lane reduce over n.
// Fused epilogue: y = (sum_n h*C + x*D) * silu(z)
__global__ __launch_bounds__(256) void scan_kernel(const float* __restrict__ dt,
                                                   const float* __restrict__ xc,
                                                   const float* __restrict__ xdbl,
                                                   const float* __restrict__ A_log,
                                                   const float* __restrict__ Dp,
                                                   const float* __restrict__ xz,
                                                   float* __restrict__ y) {
    int g = blockIdx.x * 256 + threadIdx.x;     // < 4*1536*16
    int n = g & 15;
    int d = (g >> 4) % DINNER;
    int b = g / (16 * DINNER);
    float a  = -expf(A_log[d * DSTATE + n]);
    float dd = Dp[d];
    float h = 0.f;
    int base = b * LL;
    for (int l = 0; l < LL; l++) {
        int rm = base + l;
        float dtv = dt[(size_t)rm * DINNER + d];
        float xv  = xc[(size_t)rm * DINNER + d];
        float Bv  = xdbl[(size_t)rm * 80 + DTRANK + n];
        float Cv  = xdbl[(size_t)rm * 80 + DTRANK + DSTATE + n];
        float sp  = (dtv > 20.f) ? dtv : log1pf(expf(dtv));
        float dA  = expf(sp * a);
        h = dA * h + (dtv * xv) * Bv;
        float c = h * Cv;
        c += __shfl_xor(c, 8);
        c += __shfl_xor(c, 4);
        c += __shfl_xor(c, 2);
        c += __shfl_xor(c, 1);
        if (n == 0) {
            float zv = xz[(size_t)rm * 3072 + DINNER + d];
            float sz = zv / (1.f + expf(-zv));
            y[(size_t)rm * DINNER + d] = (c + xv * dd) * sz;
        }
    }
}

extern "C" void kernel_launch(void* const* d_in, const int* in_sizes, int n_in,
                              void* d_out, int out_size, void* d_ws, size_t ws_size,
                              hipStream_t stream) {
    const float* hs        = (const float*)d_in[0];
    const float* norm_w    = (const float*)d_in[1];
    const float* in_proj_w = (const float*)d_in[2];
    const float* conv_w    = (const float*)d_in[3];
    const float* conv_b    = (const float*)d_in[4];
    const float* x_proj_w  = (const float*)d_in[5];
    const float* dt_proj_w = (const float*)d_in[6];
    const float* A_log     = (const float*)d_in[7];
    const float* D_param   = (const float*)d_in[8];
    const float* out_proj_w= (const float*)d_in[9];
    float* out = (float*)d_out;

    float* ws    = (float*)d_ws;
    float* h     = ws;                     // 4096*768   = 3145728
    float* xz    = h     + 3145728;        // 4096*3072  = 12582912
    float* xconv = xz    + 12582912;       // 4096*1536  = 6291456
    float* xdbl  = xconv + 6291456;        // 4096*80    = 327680
    float* dtb   = xdbl  + 327680;         // 4096*1536  = 6291456
    float* yb    = dtb   + 6291456;        // 4096*1536  = 6291456
    // total 34,930,688 floats ~= 140 MB of d_ws

    rmsnorm_kernel<<<NROWS / 4, 256, 0, stream>>>(hs, norm_w, h);
    // xz = h @ in_proj_w.T  (4096 x 3072, K=768)
    gemm_bt<<<dim3(3072 / 64, NROWS / 64), 256, 0, stream>>>(
        h, DMODEL, in_proj_w, DMODEL, nullptr, xz, 2 * DINNER, NROWS, 2 * DINNER, DMODEL);
    // causal dwconv + silu on x half
    conv_silu_kernel<<<(NROWS * DINNER) / 256, 256, 0, stream>>>(xz, conv_w, conv_b, xconv);
    // x_dbl = xconv @ x_proj_w.T  (4096 x 80, K=1536)
    gemm_bt<<<dim3(2, NROWS / 64), 256, 0, stream>>>(
        xconv, DINNER, x_proj_w, DINNER, nullptr, xdbl, 80, NROWS, 80, DINNER);
    // dt = x_dbl[:, :48] @ dt_proj_w.T  (4096 x 1536, K=48)
    gemm_bt<<<dim3(DINNER / 64, NROWS / 64), 256, 0, stream>>>(
        xdbl, 80, dt_proj_w, DTRANK, nullptr, dtb, DINNER, NROWS, DINNER, DTRANK);
    // selective scan + gating
    scan_kernel<<<(BB * DINNER * DSTATE) / 256, 256, 0, stream>>>(
        dtb, xconv, xdbl, A_log, D_param, xz, yb);
    // out = residual + y @ out_proj_w.T  (4096 x 768, K=1536)
    gemm_bt<<<dim3(DMODEL / 64, NROWS / 64), 256, 0, stream>>>(
        yb, DINNER, out_proj_w, DINNER, hs, out, DMODEL, NROWS, DMODEL, DINNER);
}

// Round 2
// 746.359 us; speedup vs baseline: 2.3250x; 2.3250x over previous
//
#include <hip/hip_runtime.h>
#include <hip/hip_bf16.h>
#include <math.h>

// Mamba block fwd. fp32 GEMMs + chunked 3-pass selective scan.
// B=4, L=1024, d_model=768, d_inner=1536, dt_rank=48, d_state=16, d_conv=4.

#define BB 4
#define LL 1024
#define DMODEL 768
#define DSTATE 16
#define DINNER 1536
#define DTRANK 48
#define NROWS (BB*LL)   // 4096
#define EPSF 1e-5f
#define NCHUNK 32
#define CLEN 32
#define DGRPS (DINNER/256)   // 6

__device__ __forceinline__ float softplus_f(float x) {
    return (x > 20.f) ? x : __logf(1.f + __expf(x));
}
__device__ __forceinline__ float silu_f(float x) {
    return x / (1.f + __expf(-x));
}

// ---------------- RMSNorm: one wave per row (768 cols = 64 lanes * 3 float4)
__global__ __launch_bounds__(256) void rmsnorm_kernel(const float* __restrict__ x,
                                                      const float* __restrict__ w,
                                                      float* __restrict__ out) {
    int wave = threadIdx.x >> 6;
    int lane = threadIdx.x & 63;
    int row  = blockIdx.x * 4 + wave;
    const float4* xr = reinterpret_cast<const float4*>(x + (size_t)row * DMODEL);
    const float4* wr = reinterpret_cast<const float4*>(w);
    float4 v[3];
    float ss = 0.f;
#pragma unroll
    for (int i = 0; i < 3; i++) {
        v[i] = xr[lane + i * 64];
        ss += v[i].x*v[i].x + v[i].y*v[i].y + v[i].z*v[i].z + v[i].w*v[i].w;
    }
#pragma unroll
    for (int m = 1; m < 64; m <<= 1) ss += __shfl_xor(ss, m);
    float scale = rsqrtf(ss * (1.0f / DMODEL) + EPSF);
    float4* orow = reinterpret_cast<float4*>(out + (size_t)row * DMODEL);
#pragma unroll
    for (int i = 0; i < 3; i++) {
        float4 wv = wr[lane + i * 64];
        float4 o;
        o.x = v[i].x * scale * wv.x;
        o.y = v[i].y * scale * wv.y;
        o.z = v[i].z * scale * wv.z;
        o.w = v[i].w * scale * wv.w;
        orow[lane + i * 64] = o;
    }
}

// ---------------- Generic tiled fp32 GEMM: C[M][N] = A[M][K] * W[N][K]^T (+Res)
__global__ __launch_bounds__(256) void gemm_bt(const float* __restrict__ A, int lda,
                                               const float* __restrict__ W, int ldw,
                                               const float* __restrict__ Res,
                                               float* __restrict__ C, int ldc,
                                               int M, int N, int K) {
    __shared__ float As[16][68];
    __shared__ float Ws[16][68];
    int tid = threadIdx.x;
    int tx = tid & 15, ty = tid >> 4;
    int m0 = blockIdx.y * 64, n0 = blockIdx.x * 64;
    int lrow = tid >> 2;
    int lk   = (tid & 3) * 4;
    int arow = m0 + lrow;
    int wrow = n0 + lrow;
    bool wvalid = (wrow < N);
    float acc[4][4] = {};

    for (int k0 = 0; k0 < K; k0 += 16) {
        float4 av = *reinterpret_cast<const float4*>(A + (size_t)arow * lda + k0 + lk);
        float4 wv = wvalid ? *reinterpret_cast<const float4*>(W + (size_t)wrow * ldw + k0 + lk)
                           : make_float4(0.f, 0.f, 0.f, 0.f);
        __syncthreads();
        As[lk+0][lrow] = av.x; As[lk+1][lrow] = av.y; As[lk+2][lrow] = av.z; As[lk+3][lrow] = av.w;
        Ws[lk+0][lrow] = wv.x; Ws[lk+1][lrow] = wv.y; Ws[lk+2][lrow] = wv.z; Ws[lk+3][lrow] = wv.w;
        __syncthreads();
#pragma unroll
        for (int kk = 0; kk < 16; kk++) {
            float4 a = *reinterpret_cast<const float4*>(&As[kk][ty * 4]);
            float4 w = *reinterpret_cast<const float4*>(&Ws[kk][tx * 4]);
            acc[0][0] += a.x * w.x; acc[0][1] += a.x * w.y; acc[0][2] += a.x * w.z; acc[0][3] += a.x * w.w;
            acc[1][0] += a.y * w.x; acc[1][1] += a.y * w.y; acc[1][2] += a.y * w.z; acc[1][3] += a.y * w.w;
            acc[2][0] += a.z * w.x; acc[2][1] += a.z * w.y; acc[2][2] += a.z * w.z; acc[2][3] += a.z * w.w;
            acc[3][0] += a.w * w.x; acc[3][1] += a.w * w.y; acc[3][2] += a.w * w.z; acc[3][3] += a.w * w.w;
        }
    }

#pragma unroll
    for (int i = 0; i < 4; i++) {
        int row = m0 + ty * 4 + i;
        int col = n0 + tx * 4;
        if (col < N) {
            float4 o = make_float4(acc[i][0], acc[i][1], acc[i][2], acc[i][3]);
            if (Res) {
                float4 r = *reinterpret_cast<const float4*>(Res + (size_t)row * ldc + col);
                o.x += r.x; o.y += r.y; o.z += r.z; o.w += r.w;
            }
            *reinterpret_cast<float4*>(C + (size_t)row * ldc + col) = o;
        }
    }
}

// ---------------- causal depthwise conv (k=4) + bias + SiLU
__global__ __launch_bounds__(256) void conv_silu_kernel(const float* __restrict__ xz,
                                                        const float* __restrict__ cw,
                                                        const float* __restrict__ cb,
                                                        float* __restrict__ out) {
    int idx = blockIdx.x * 256 + threadIdx.x;   // < 4096*1536
    int d  = idx % DINNER;
    int ml = idx / DINNER;
    int l  = ml % LL;
    float acc = cb[d];
#pragma unroll
    for (int i = 0; i < 4; i++) {
        int li = l - 3 + i;
        if (li >= 0) acc += xz[(size_t)(ml - 3 + i) * 3072 + d] * cw[d * 4 + i];
    }
    out[idx] = silu_f(acc);
}

// ---------------- selective scan, chunked 3-pass.
// Pass 1: per (b,chunk,d): local scan from h=0 over CLEN steps.
// Stores h_end[16] and sum_sp (chunk dA-product = exp(a_n * sum_sp)).
__global__ __launch_bounds__(256) void scan_pass1(
        const float* __restrict__ dt, const float* __restrict__ xc,
        const float* __restrict__ xdbl, const float* __restrict__ A_log,
        float* __restrict__ hend, float* __restrict__ ssp) {
    __shared__ float Bs[CLEN][DSTATE];
    int tid = threadIdx.x;
    int dgrp = blockIdx.x % DGRPS;
    int chunk = (blockIdx.x / DGRPS) % NCHUNK;
    int b = blockIdx.x / (DGRPS * NCHUNK);
    int d = dgrp * 256 + tid;
    int rbase = b * LL + chunk * CLEN;
    for (int idx = tid; idx < CLEN * DSTATE; idx += 256) {
        int t = idx >> 4, j = idx & 15;
        Bs[t][j] = xdbl[(size_t)(rbase + t) * 80 + DTRANK + j];
    }
    float a[16];
    const float4* ar = reinterpret_cast<const float4*>(A_log + (size_t)d * 16);
#pragma unroll
    for (int i = 0; i < 4; i++) {
        float4 v = ar[i];
        a[4*i+0] = -__expf(v.x); a[4*i+1] = -__expf(v.y);
        a[4*i+2] = -__expf(v.z); a[4*i+3] = -__expf(v.w);
    }
    __syncthreads();
    float h[16];
#pragma unroll
    for (int n = 0; n < 16; n++) h[n] = 0.f;
    float sum_sp = 0.f;
    for (int t = 0; t < CLEN; t++) {
        int rm = rbase + t;
        float dtv = dt[(size_t)rm * DINNER + d];
        float xv  = xc[(size_t)rm * DINNER + d];
        float sp  = softplus_f(dtv);
        sum_sp += sp;
        float du = dtv * xv;
#pragma unroll
        for (int n = 0; n < 16; n++)
            h[n] = __expf(sp * a[n]) * h[n] + du * Bs[t][n];
    }
    size_t o = (size_t)(b * NCHUNK + chunk) * DINNER + d;
    float4* ho = reinterpret_cast<float4*>(hend + o * 16);
#pragma unroll
    for (int i = 0; i < 4; i++)
        ho[i] = make_float4(h[4*i], h[4*i+1], h[4*i+2], h[4*i+3]);
    ssp[o] = sum_sp;
}

// Pass 2: stitch chunks. Thread per (b,d,n); 32 sequential chunk combines.
__global__ __launch_bounds__(256) void scan_pass2(
        const float* __restrict__ hend, const float* __restrict__ ssp,
        const float* __restrict__ A_log, float* __restrict__ hini) {
    int g = blockIdx.x * 256 + threadIdx.x;   // < 4*1536*16
    int n = g & 15;
    int d = (g >> 4) % DINNER;
    int b = g / (16 * DINNER);
    float a = -__expf(A_log[(size_t)d * 16 + n]);
    float h = 0.f;
    for (int c = 0; c < NCHUNK; c++) {
        size_t o = (size_t)(b * NCHUNK + c) * DINNER + d;
        hini[o * 16 + n] = h;
        h = __expf(a * ssp[o]) * h + hend[o * 16 + n];
    }
}

// Pass 3: re-run local scans from correct init; fused epilogue
// y = (sum_n h*C + x*D) * silu(z), coalesced store.
__global__ __launch_bounds__(256) void scan_pass3(
        const float* __restrict__ dt, const float* __restrict__ xc,
        const float* __restrict__ xdbl, const float* __restrict__ A_log,
        const float* __restrict__ Dp, const float* __restrict__ xz,
        const float* __restrict__ hini, float* __restrict__ y) {
    __shared__ float BCs[CLEN][2*DSTATE];
    int tid = threadIdx.x;
    int dgrp = blockIdx.x % DGRPS;
    int chunk = (blockIdx.x / DGRPS) % NCHUNK;
    int b = blockIdx.x / (DGRPS * NCHUNK);
    int d = dgrp * 256 + tid;
    int rbase = b * LL + chunk * CLEN;
    for (int idx = tid; idx < CLEN * 2 * DSTATE; idx += 256) {
        int t = idx >> 5, j = idx & 31;
        BCs[t][j] = xdbl[(size_t)(rbase + t) * 80 + DTRANK + j];
    }
    float a[16];
    const float4* ar = reinterpret_cast<const float4*>(A_log + (size_t)d * 16);
#pragma unroll
    for (int i = 0; i < 4; i++) {
        float4 v = ar[i];
        a[4*i+0] = -__expf(v.x); a[4*i+1] = -__expf(v.y);
        a[4*i+2] = -__expf(v.z); a[4*i+3] = -__expf(v.w);
    }
    float dD = Dp[d];
    float h[16];
    size_t o = (size_t)(b * NCHUNK + chunk) * DINNER + d;
    const float4* hi = reinterpret_cast<const float4*>(hini + o * 16);
#pragma unroll
    for (int i = 0; i < 4; i++) {
        float4 v = hi[i];
        h[4*i] = v.x; h[4*i+1] = v.y; h[4*i+2] = v.z; h[4*i+3] = v.w;
    }
    __syncthreads();
    for (int t = 0; t < CLEN; t++) {
        int rm = rbase + t;
        float dtv = dt[(size_t)rm * DINNER + d];
        float xv  = xc[(size_t)rm * DINNER + d];
        float zv  = xz[(size_t)rm * 2 * DINNER + DINNER + d];
        float sp  = softplus_f(dtv);
        float du  = dtv * xv;
        float acc = 0.f;
#pragma unroll
        for (int n = 0; n < 16; n++) {
            h[n] = __expf(sp * a[n]) * h[n] + du * BCs[t][n];
            acc += h[n] * BCs[t][DSTATE + n];
        }
        y[(size_t)rm * DINNER + d] = (acc + xv * dD) * silu_f(zv);
    }
}

extern "C" void kernel_launch(void* const* d_in, const int* in_sizes, int n_in,
                              void* d_out, int out_size, void* d_ws, size_t ws_size,
                              hipStream_t stream) {
    const float* hs        = (const float*)d_in[0];
    const float* norm_w    = (const float*)d_in[1];
    const float* in_proj_w = (const float*)d_in[2];
    const float* conv_w    = (const float*)d_in[3];
    const float* conv_b    = (const float*)d_in[4];
    const float* x_proj_w  = (const float*)d_in[5];
    const float* dt_proj_w = (const float*)d_in[6];
    const float* A_log     = (const float*)d_in[7];
    const float* D_param   = (const float*)d_in[8];
    const float* out_proj_w= (const float*)d_in[9];
    float* out = (float*)d_out;

    float* ws    = (float*)d_ws;
    float* h     = ws;                     // 4096*768   = 3,145,728 (reused as hend)
    float* xz    = h     + 3145728;        // 4096*3072  = 12,582,912
    float* xconv = xz    + 12582912;       // 4096*1536  = 6,291,456
    float* xdbl  = xconv + 6291456;        // 4096*80    = 327,680
    float* dtb   = xdbl  + 327680;         // 4096*1536  = 6,291,456
    float* yb    = dtb   + 6291456;        // 4096*1536  = 6,291,456
    float* hini  = yb    + 6291456;        // 4*32*1536*16 = 3,145,728
    float* ssp   = hini  + 3145728;        // 4*32*1536  = 196,608
    float* hend  = h;                      // alias: h dead after in_proj GEMM

    rmsnorm_kernel<<<NROWS / 4, 256, 0, stream>>>(hs, norm_w, h);
    // xz = h @ in_proj_w.T  (4096 x 3072, K=768)
    gemm_bt<<<dim3(3072 / 64, NROWS / 64), 256, 0, stream>>>(
        h, DMODEL, in_proj_w, DMODEL, nullptr, xz, 2 * DINNER, NROWS, 2 * DINNER, DMODEL);
    // causal dwconv + silu on x half
    conv_silu_kernel<<<(NROWS * DINNER) / 256, 256, 0, stream>>>(xz, conv_w, conv_b, xconv);
    // x_dbl = xconv @ x_proj_w.T  (4096 x 80, K=1536)
    gemm_bt<<<dim3(2, NROWS / 64), 256, 0, stream>>>(
        xconv, DINNER, x_proj_w, DINNER, nullptr, xdbl, 80, NROWS, 80, DINNER);
    // dt = x_dbl[:, :48] @ dt_proj_w.T  (4096 x 1536, K=48)
    gemm_bt<<<dim3(DINNER / 64, NROWS / 64), 256, 0, stream>>>(
        xdbl, 80, dt_proj_w, DTRANK, nullptr, dtb, DINNER, NROWS, DINNER, DTRANK);
    // chunked selective scan
    scan_pass1<<<BB * NCHUNK * DGRPS, 256, 0, stream>>>(dtb, xconv, xdbl, A_log, hend, ssp);
    scan_pass2<<<(BB * DINNER * DSTATE) / 256, 256, 0, stream>>>(hend, ssp, A_log, hini);
    scan_pass3<<<BB * NCHUNK * DGRPS, 256, 0, stream>>>(dtb, xconv, xdbl, A_log, D_param,
                                                        xz, hini, yb);
    // out = residual + y @ out_proj_w.T  (4096 x 768, K=1536)
    gemm_bt<<<dim3(DMODEL / 64, NROWS / 64), 256, 0, stream>>>(
        yb, DINNER, out_proj_w, DINNER, hs, out, DMODEL, NROWS, DMODEL, DINNER);
}

// Round 3
// 389.337 us; speedup vs baseline: 4.4570x; 1.9170x over previous
//
#include <hip/hip_runtime.h>
#include <hip/hip_bf16.h>
#include <math.h>

// Mamba block fwd. bf16-MFMA big GEMMs + fp32 small GEMMs + chunked 3-pass scan.
// B=4, L=1024, d_model=768, d_inner=1536, dt_rank=48, d_state=16, d_conv=4.

#define BB 4
#define LL 1024
#define DMODEL 768
#define DSTATE 16
#define DINNER 1536
#define DTRANK 48
#define NROWS (BB*LL)   // 4096
#define EPSF 1e-5f
#define NCHUNK 32
#define CLEN 32
#define DGRPS (DINNER/256)   // 6

typedef __attribute__((ext_vector_type(8))) short bf16x8;
typedef __attribute__((ext_vector_type(4))) float f32x4;

__device__ __forceinline__ float softplus_f(float x) {
    return (x > 20.f) ? x : __logf(1.f + __expf(x));
}
__device__ __forceinline__ float silu_f(float x) {
    return x / (1.f + __expf(-x));
}
__device__ __forceinline__ ushort f2bf(float x) {
    union { float f; uint32_t u; } v; v.f = x;
    uint32_t r = v.u + 0x7FFF + ((v.u >> 16) & 1);   // round-to-nearest-even
    return (ushort)(r >> 16);
}

// ---------------- fp32 -> bf16, x8 vectorized (n divisible by 8)
__global__ __launch_bounds__(256) void f32_to_bf16_x8(const float* __restrict__ in,
                                                      ushort* __restrict__ out, int n8) {
    int i = blockIdx.x * 256 + threadIdx.x;
    if (i >= n8) return;
    const float4* ip = reinterpret_cast<const float4*>(in) + (size_t)i * 2;
    float4 v0 = ip[0], v1 = ip[1];
    uint4 o;
    o.x = (uint32_t)f2bf(v0.x) | ((uint32_t)f2bf(v0.y) << 16);
    o.y = (uint32_t)f2bf(v0.z) | ((uint32_t)f2bf(v0.w) << 16);
    o.z = (uint32_t)f2bf(v1.x) | ((uint32_t)f2bf(v1.y) << 16);
    o.w = (uint32_t)f2bf(v1.z) | ((uint32_t)f2bf(v1.w) << 16);
    reinterpret_cast<uint4*>(out)[i] = o;
}

// ---------------- RMSNorm: one wave per row; writes bf16
__global__ __launch_bounds__(256) void rmsnorm_kernel(const float* __restrict__ x,
                                                      const float* __restrict__ w,
                                                      ushort* __restrict__ out) {
    int wave = threadIdx.x >> 6;
    int lane = threadIdx.x & 63;
    int row  = blockIdx.x * 4 + wave;
    const float4* xr = reinterpret_cast<const float4*>(x + (size_t)row * DMODEL);
    const float4* wr = reinterpret_cast<const float4*>(w);
    float4 v[3];
    float ss = 0.f;
#pragma unroll
    for (int i = 0; i < 3; i++) {
        v[i] = xr[lane + i * 64];
        ss += v[i].x*v[i].x + v[i].y*v[i].y + v[i].z*v[i].z + v[i].w*v[i].w;
    }
#pragma unroll
    for (int m = 1; m < 64; m <<= 1) ss += __shfl_xor(ss, m);
    float scale = rsqrtf(ss * (1.0f / DMODEL) + EPSF);
    ushort4* orow = reinterpret_cast<ushort4*>(out + (size_t)row * DMODEL);
#pragma unroll
    for (int i = 0; i < 3; i++) {
        float4 wv = wr[lane + i * 64];
        ushort4 o;
        o.x = f2bf(v[i].x * scale * wv.x);
        o.y = f2bf(v[i].y * scale * wv.y);
        o.z = f2bf(v[i].z * scale * wv.z);
        o.w = f2bf(v[i].w * scale * wv.w);
        orow[lane + i * 64] = o;
    }
}

// ---------------- bf16 MFMA GEMM: C[M][N] = A[M][K] @ W[N][K]^T (+Res), fp32 out.
// 128x128 tile, BK=32, 256 thr = 4 waves (2x2), 4x4 16x16x32 frags/wave.
// M,N multiples of 128; K multiple of 32.
__global__ __launch_bounds__(256) void gemm_bf16_bt(
        const ushort* __restrict__ A, int lda,
        const ushort* __restrict__ W, int ldw,
        const float* __restrict__ Res,
        float* __restrict__ C, int ldc, int K) {
    __shared__ ushort As[128 * 32];
    __shared__ ushort Bs[128 * 32];
    int t = threadIdx.x;
    int m0 = blockIdx.y * 128, n0 = blockIdx.x * 128;
    int srow = t >> 2;             // 0..63
    int scol = (t & 3) * 8;        // 0,8,16,24
    int lane = t & 63;
    int wid  = t >> 6;
    int wr = wid >> 1, wc = wid & 1;
    int fr = lane & 15;            // frag row (A) / col (B,C)
    int fq = lane >> 4;            // k-chunk (in), row-group (out)

    const ushort* Ap = A + (size_t)(m0 + srow) * lda + scol;
    const ushort* Wp = W + (size_t)(n0 + srow) * ldw + scol;
    int sdst = srow * 32 + scol;

    int aoff[4], boff[4];
#pragma unroll
    for (int m = 0; m < 4; m++) aoff[m] = (wr * 64 + m * 16 + fr) * 32 + fq * 8;
#pragma unroll
    for (int n = 0; n < 4; n++) boff[n] = (wc * 64 + n * 16 + fr) * 32 + fq * 8;

    f32x4 acc[4][4];
#pragma unroll
    for (int m = 0; m < 4; m++)
#pragma unroll
        for (int n = 0; n < 4; n++)
#pragma unroll
            for (int r = 0; r < 4; r++) acc[m][n][r] = 0.f;

    for (int k0 = 0; k0 < K; k0 += 32) {
        uint4 a0 = *reinterpret_cast<const uint4*>(Ap + k0);
        uint4 a1 = *reinterpret_cast<const uint4*>(Ap + (size_t)64 * lda + k0);
        uint4 b0 = *reinterpret_cast<const uint4*>(Wp + k0);
        uint4 b1 = *reinterpret_cast<const uint4*>(Wp + (size_t)64 * ldw + k0);
        __syncthreads();
        *reinterpret_cast<uint4*>(&As[sdst])            = a0;
        *reinterpret_cast<uint4*>(&As[sdst + 64 * 32])  = a1;
        *reinterpret_cast<uint4*>(&Bs[sdst])            = b0;
        *reinterpret_cast<uint4*>(&Bs[sdst + 64 * 32])  = b1;
        __syncthreads();
        bf16x8 af[4], bf[4];
#pragma unroll
        for (int m = 0; m < 4; m++) af[m] = *reinterpret_cast<const bf16x8*>(&As[aoff[m]]);
#pragma unroll
        for (int n = 0; n < 4; n++) bf[n] = *reinterpret_cast<const bf16x8*>(&Bs[boff[n]]);
#pragma unroll
        for (int m = 0; m < 4; m++)
#pragma unroll
            for (int n = 0; n < 4; n++)
                acc[m][n] = __builtin_amdgcn_mfma_f32_16x16x32_bf16(af[m], bf[n], acc[m][n], 0, 0, 0);
    }

#pragma unroll
    for (int m = 0; m < 4; m++) {
#pragma unroll
        for (int n = 0; n < 4; n++) {
            int col = n0 + wc * 64 + n * 16 + fr;
#pragma unroll
            for (int r = 0; r < 4; r++) {
                int row = m0 + wr * 64 + m * 16 + fq * 4 + r;
                float v = acc[m][n][r];
                if (Res) v += Res[(size_t)row * ldc + col];
                C[(size_t)row * ldc + col] = v;
            }
        }
    }
}

// ---------------- Generic tiled fp32 GEMM (small GEMMs): C = A @ W^T (+Res)
__global__ __launch_bounds__(256) void gemm_bt(const float* __restrict__ A, int lda,
                                               const float* __restrict__ W, int ldw,
                                               const float* __restrict__ Res,
                                               float* __restrict__ C, int ldc,
                                               int M, int N, int K) {
    __shared__ float As[16][68];
    __shared__ float Ws[16][68];
    int tid = threadIdx.x;
    int tx = tid & 15, ty = tid >> 4;
    int m0 = blockIdx.y * 64, n0 = blockIdx.x * 64;
    int lrow = tid >> 2;
    int lk   = (tid & 3) * 4;
    int arow = m0 + lrow;
    int wrow = n0 + lrow;
    bool wvalid = (wrow < N);
    float acc[4][4] = {};

    for (int k0 = 0; k0 < K; k0 += 16) {
        float4 av = *reinterpret_cast<const float4*>(A + (size_t)arow * lda + k0 + lk);
        float4 wv = wvalid ? *reinterpret_cast<const float4*>(W + (size_t)wrow * ldw + k0 + lk)
                           : make_float4(0.f, 0.f, 0.f, 0.f);
        __syncthreads();
        As[lk+0][lrow] = av.x; As[lk+1][lrow] = av.y; As[lk+2][lrow] = av.z; As[lk+3][lrow] = av.w;
        Ws[lk+0][lrow] = wv.x; Ws[lk+1][lrow] = wv.y; Ws[lk+2][lrow] = wv.z; Ws[lk+3][lrow] = wv.w;
        __syncthreads();
#pragma unroll
        for (int kk = 0; kk < 16; kk++) {
            float4 a = *reinterpret_cast<const float4*>(&As[kk][ty * 4]);
            float4 w = *reinterpret_cast<const float4*>(&Ws[kk][tx * 4]);
            acc[0][0] += a.x * w.x; acc[0][1] += a.x * w.y; acc[0][2] += a.x * w.z; acc[0][3] += a.x * w.w;
            acc[1][0] += a.y * w.x; acc[1][1] += a.y * w.y; acc[1][2] += a.y * w.z; acc[1][3] += a.y * w.w;
            acc[2][0] += a.z * w.x; acc[2][1] += a.z * w.y; acc[2][2] += a.z * w.z; acc[2][3] += a.z * w.w;
            acc[3][0] += a.w * w.x; acc[3][1] += a.w * w.y; acc[3][2] += a.w * w.z; acc[3][3] += a.w * w.w;
        }
    }

#pragma unroll
    for (int i = 0; i < 4; i++) {
        int row = m0 + ty * 4 + i;
        int col = n0 + tx * 4;
        if (col < N) {
            float4 o = make_float4(acc[i][0], acc[i][1], acc[i][2], acc[i][3]);
            if (Res) {
                float4 r = *reinterpret_cast<const float4*>(Res + (size_t)row * ldc + col);
                o.x += r.x; o.y += r.y; o.z += r.z; o.w += r.w;
            }
            *reinterpret_cast<float4*>(C + (size_t)row * ldc + col) = o;
        }
    }
}

// ---------------- causal depthwise conv (k=4) + bias + SiLU
__global__ __launch_bounds__(256) void conv_silu_kernel(const float* __restrict__ xz,
                                                        const float* __restrict__ cw,
                                                        const float* __restrict__ cb,
                                                        float* __restrict__ out) {
    int idx = blockIdx.x * 256 + threadIdx.x;   // < 4096*1536
    int d  = idx % DINNER;
    int ml = idx / DINNER;
    int l  = ml % LL;
    float acc = cb[d];
#pragma unroll
    for (int i = 0; i < 4; i++) {
        int li = l - 3 + i;
        if (li >= 0) acc += xz[(size_t)(ml - 3 + i) * 3072 + d] * cw[d * 4 + i];
    }
    out[idx] = silu_f(acc);
}

// ---------------- selective scan, chunked 3-pass.
__global__ __launch_bounds__(256) void scan_pass1(
        const float* __restrict__ dt, const float* __restrict__ xc,
        const float* __restrict__ xdbl, const float* __restrict__ A_log,
        float* __restrict__ hend, float* __restrict__ ssp) {
    __shared__ float Bs[CLEN][DSTATE];
    int tid = threadIdx.x;
    int dgrp = blockIdx.x % DGRPS;
    int chunk = (blockIdx.x / DGRPS) % NCHUNK;
    int b = blockIdx.x / (DGRPS * NCHUNK);
    int d = dgrp * 256 + tid;
    int rbase = b * LL + chunk * CLEN;
    for (int idx = tid; idx < CLEN * DSTATE; idx += 256) {
        int t = idx >> 4, j = idx & 15;
        Bs[t][j] = xdbl[(size_t)(rbase + t) * 80 + DTRANK + j];
    }
    float a[16];
    const float4* ar = reinterpret_cast<const float4*>(A_log + (size_t)d * 16);
#pragma unroll
    for (int i = 0; i < 4; i++) {
        float4 v = ar[i];
        a[4*i+0] = -__expf(v.x); a[4*i+1] = -__expf(v.y);
        a[4*i+2] = -__expf(v.z); a[4*i+3] = -__expf(v.w);
    }
    __syncthreads();
    float h[16];
#pragma unroll
    for (int n = 0; n < 16; n++) h[n] = 0.f;
    float sum_sp = 0.f;
    for (int t = 0; t < CLEN; t++) {
        int rm = rbase + t;
        float dtv = dt[(size_t)rm * DINNER + d];
        float xv  = xc[(size_t)rm * DINNER + d];
        float sp  = softplus_f(dtv);
        sum_sp += sp;
        float du = dtv * xv;
#pragma unroll
        for (int n = 0; n < 16; n++)
            h[n] = __expf(sp * a[n]) * h[n] + du * Bs[t][n];
    }
    size_t o = (size_t)(b * NCHUNK + chunk) * DINNER + d;
    float4* ho = reinterpret_cast<float4*>(hend + o * 16);
#pragma unroll
    for (int i = 0; i < 4; i++)
        ho[i] = make_float4(h[4*i], h[4*i+1], h[4*i+2], h[4*i+3]);
    ssp[o] = sum_sp;
}

__global__ __launch_bounds__(256) void scan_pass2(
        const float* __restrict__ hend, const float* __restrict__ ssp,
        const float* __restrict__ A_log, float* __restrict__ hini) {
    int g = blockIdx.x * 256 + threadIdx.x;   // < 4*1536*16
    int n = g & 15;
    int d = (g >> 4) % DINNER;
    int b = g / (16 * DINNER);
    float a = -__expf(A_log[(size_t)d * 16 + n]);
    float h = 0.f;
    for (int c = 0; c < NCHUNK; c++) {
        size_t o = (size_t)(b * NCHUNK + c) * DINNER + d;
        hini[o * 16 + n] = h;
        h = __expf(a * ssp[o]) * h + hend[o * 16 + n];
    }
}

// Pass 3: fused epilogue y = (sum_n h*C + x*D) * silu(z) -> bf16
__global__ __launch_bounds__(256) void scan_pass3(
        const float* __restrict__ dt, const float* __restrict__ xc,
        const float* __restrict__ xdbl, const float* __restrict__ A_log,
        const float* __restrict__ Dp, const float* __restrict__ xz,
        const float* __restrict__ hini, ushort* __restrict__ y) {
    __shared__ float BCs[CLEN][2*DSTATE];
    int tid = threadIdx.x;
    int dgrp = blockIdx.x % DGRPS;
    int chunk = (blockIdx.x / DGRPS) % NCHUNK;
    int b = blockIdx.x / (DGRPS * NCHUNK);
    int d = dgrp * 256 + tid;
    int rbase = b * LL + chunk * CLEN;
    for (int idx = tid; idx < CLEN * 2 * DSTATE; idx += 256) {
        int t = idx >> 5, j = idx & 31;
        BCs[t][j] = xdbl[(size_t)(rbase + t) * 80 + DTRANK + j];
    }
    float a[16];
    const float4* ar = reinterpret_cast<const float4*>(A_log + (size_t)d * 16);
#pragma unroll
    for (int i = 0; i < 4; i++) {
        float4 v = ar[i];
        a[4*i+0] = -__expf(v.x); a[4*i+1] = -__expf(v.y);
        a[4*i+2] = -__expf(v.z); a[4*i+3] = -__expf(v.w);
    }
    float dD = Dp[d];
    float h[16];
    size_t o = (size_t)(b * NCHUNK + chunk) * DINNER + d;
    const float4* hi = reinterpret_cast<const float4*>(hini + o * 16);
#pragma unroll
    for (int i = 0; i < 4; i++) {
        float4 v = hi[i];
        h[4*i] = v.x; h[4*i+1] = v.y; h[4*i+2] = v.z; h[4*i+3] = v.w;
    }
    __syncthreads();
    for (int t = 0; t < CLEN; t++) {
        int rm = rbase + t;
        float dtv = dt[(size_t)rm * DINNER + d];
        float xv  = xc[(size_t)rm * DINNER + d];
        float zv  = xz[(size_t)rm * 2 * DINNER + DINNER + d];
        float sp  = softplus_f(dtv);
        float du  = dtv * xv;
        float acc = 0.f;
#pragma unroll
        for (int n = 0; n < 16; n++) {
            h[n] = __expf(sp * a[n]) * h[n] + du * BCs[t][n];
            acc += h[n] * BCs[t][DSTATE + n];
        }
        y[(size_t)rm * DINNER + d] = f2bf((acc + xv * dD) * silu_f(zv));
    }
}

extern "C" void kernel_launch(void* const* d_in, const int* in_sizes, int n_in,
                              void* d_out, int out_size, void* d_ws, size_t ws_size,
                              hipStream_t stream) {
    const float* hs        = (const float*)d_in[0];
    const float* norm_w    = (const float*)d_in[1];
    const float* in_proj_w = (const float*)d_in[2];
    const float* conv_w    = (const float*)d_in[3];
    const float* conv_b    = (const float*)d_in[4];
    const float* x_proj_w  = (const float*)d_in[5];
    const float* dt_proj_w = (const float*)d_in[6];
    const float* A_log     = (const float*)d_in[7];
    const float* D_param   = (const float*)d_in[8];
    const float* out_proj_w= (const float*)d_in[9];
    float* out = (float*)d_out;

    float* ws = (float*)d_ws;
    // slotA (3,145,728 f32): h_bf (ushort) early, hend (f32) later — disjoint lifetimes
    ushort* h_bf = (ushort*)ws;
    float*  hend = ws;
    float* xz    = ws + 3145728;           // 4096*3072 f32
    float* xconv = xz + 12582912;          // 4096*1536 f32
    float* xdbl  = xconv + 6291456;        // 4096*80 f32
    float* dtb   = xdbl + 327680;          // 4096*1536 f32
    ushort* y_bf = (ushort*)(dtb + 6291456);       // 4096*1536 ushort (3,145,728 f32 slot)
    float* hini  = dtb + 6291456 + 3145728;        // 4*32*1536*16 f32
    float* ssp   = hini + 3145728;                 // 4*32*1536 f32
    ushort* w_in_bf  = (ushort*)(ssp + 196608);            // 3072*768 ushort
    ushort* w_out_bf = (ushort*)(ssp + 196608 + 1179648);  // 768*1536 ushort
    // total 36,896,768 f32 = 147.6 MB

    // weight conversions
    f32_to_bf16_x8<<<(2359296/8 + 255)/256, 256, 0, stream>>>(in_proj_w, w_in_bf, 2359296/8);
    f32_to_bf16_x8<<<(1179648/8 + 255)/256, 256, 0, stream>>>(out_proj_w, w_out_bf, 1179648/8);

    rmsnorm_kernel<<<NROWS / 4, 256, 0, stream>>>(hs, norm_w, h_bf);
    // xz = h @ in_proj_w.T  (4096 x 3072, K=768) — bf16 MFMA
    gemm_bf16_bt<<<dim3(3072/128, NROWS/128), 256, 0, stream>>>(
        h_bf, DMODEL, w_in_bf, DMODEL, nullptr, xz, 2 * DINNER, DMODEL);
    // causal dwconv + silu on x half
    conv_silu_kernel<<<(NROWS * DINNER) / 256, 256, 0, stream>>>(xz, conv_w, conv_b, xconv);
    // x_dbl = xconv @ x_proj_w.T  (4096 x 80, K=1536) — fp32
    gemm_bt<<<dim3(2, NROWS / 64), 256, 0, stream>>>(
        xconv, DINNER, x_proj_w, DINNER, nullptr, xdbl, 80, NROWS, 80, DINNER);
    // dt = x_dbl[:, :48] @ dt_proj_w.T  (4096 x 1536, K=48) — fp32
    gemm_bt<<<dim3(DINNER / 64, NROWS / 64), 256, 0, stream>>>(
        xdbl, 80, dt_proj_w, DTRANK, nullptr, dtb, DINNER, NROWS, DINNER, DTRANK);
    // chunked selective scan
    scan_pass1<<<BB * NCHUNK * DGRPS, 256, 0, stream>>>(dtb, xconv, xdbl, A_log, hend, ssp);
    scan_pass2<<<(BB * DINNER * DSTATE) / 256, 256, 0, stream>>>(hend, ssp, A_log, hini);
    scan_pass3<<<BB * NCHUNK * DGRPS, 256, 0, stream>>>(dtb, xconv, xdbl, A_log, D_param,
                                                        xz, hini, y_bf);
    // out = residual + y @ out_proj_w.T  (4096 x 768, K=1536) — bf16 MFMA
    gemm_bf16_bt<<<dim3(DMODEL/128, NROWS/128), 256, 0, stream>>>(
        y_bf, DINNER, w_out_bf, DINNER, hs, out, DMODEL, DINNER);
}

// Round 4
// 303.361 us; speedup vs baseline: 5.7201x; 1.2834x over previous
//
#include <hip/hip_runtime.h>
#include <hip/hip_bf16.h>
#include <math.h>

// Mamba block fwd. bf16-MFMA GEMMs (in/out/x_proj) + fp32 dt GEMM + chunked 3-pass scan.
// B=4, L=1024, d_model=768, d_inner=1536, dt_rank=48, d_state=16, d_conv=4.

#define BB 4
#define LL 1024
#define DMODEL 768
#define DSTATE 16
#define DINNER 1536
#define DTRANK 48
#define NROWS (BB*LL)   // 4096
#define EPSF 1e-5f
#define NCHUNK 32
#define CLEN 32
#define DGRPS (DINNER/256)   // 6
#define XP_SPLITK 4
#define XPK (DINNER/XP_SPLITK)   // 384

typedef __attribute__((ext_vector_type(8))) short bf16x8;
typedef __attribute__((ext_vector_type(8))) ushort ushort8;
typedef __attribute__((ext_vector_type(4))) float f32x4;

__device__ __forceinline__ float softplus_f(float x) {
    return (x > 20.f) ? x : __logf(1.f + __expf(x));
}
__device__ __forceinline__ float silu_f(float x) {
    return x / (1.f + __expf(-x));
}
__device__ __forceinline__ ushort f2bf(float x) {
    union { float f; uint32_t u; } v; v.f = x;
    uint32_t r = v.u + 0x7FFF + ((v.u >> 16) & 1);   // round-to-nearest-even
    return (ushort)(r >> 16);
}
__device__ __forceinline__ float bf2f(ushort u) {
    union { uint32_t u; float f; } v; v.u = ((uint32_t)u) << 16;
    return v.f;
}

// ---------------- fp32 -> bf16, x8 vectorized (n8 = n/8)
__global__ __launch_bounds__(256) void f32_to_bf16_x8(const float* __restrict__ in,
                                                      ushort* __restrict__ out, int n8) {
    int i = blockIdx.x * 256 + threadIdx.x;
    if (i >= n8) return;
    const float4* ip = reinterpret_cast<const float4*>(in) + (size_t)i * 2;
    float4 v0 = ip[0], v1 = ip[1];
    uint4 o;
    o.x = (uint32_t)f2bf(v0.x) | ((uint32_t)f2bf(v0.y) << 16);
    o.y = (uint32_t)f2bf(v0.z) | ((uint32_t)f2bf(v0.w) << 16);
    o.z = (uint32_t)f2bf(v1.x) | ((uint32_t)f2bf(v1.y) << 16);
    o.w = (uint32_t)f2bf(v1.z) | ((uint32_t)f2bf(v1.w) << 16);
    reinterpret_cast<uint4*>(out)[i] = o;
}

// ---------------- RMSNorm: one wave per row; writes bf16
__global__ __launch_bounds__(256) void rmsnorm_kernel(const float* __restrict__ x,
                                                      const float* __restrict__ w,
                                                      ushort* __restrict__ out) {
    int wave = threadIdx.x >> 6;
    int lane = threadIdx.x & 63;
    int row  = blockIdx.x * 4 + wave;
    const float4* xr = reinterpret_cast<const float4*>(x + (size_t)row * DMODEL);
    const float4* wr = reinterpret_cast<const float4*>(w);
    float4 v[3];
    float ss = 0.f;
#pragma unroll
    for (int i = 0; i < 3; i++) {
        v[i] = xr[lane + i * 64];
        ss += v[i].x*v[i].x + v[i].y*v[i].y + v[i].z*v[i].z + v[i].w*v[i].w;
    }
#pragma unroll
    for (int m = 1; m < 64; m <<= 1) ss += __shfl_xor(ss, m);
    float scale = rsqrtf(ss * (1.0f / DMODEL) + EPSF);
    ushort4* orow = reinterpret_cast<ushort4*>(out + (size_t)row * DMODEL);
#pragma unroll
    for (int i = 0; i < 3; i++) {
        float4 wv = wr[lane + i * 64];
        ushort4 o;
        o.x = f2bf(v[i].x * scale * wv.x);
        o.y = f2bf(v[i].y * scale * wv.y);
        o.z = f2bf(v[i].z * scale * wv.z);
        o.w = f2bf(v[i].w * scale * wv.w);
        orow[lane + i * 64] = o;
    }
}

// ---------------- bf16 MFMA GEMM: C[M][N] = A[M][K] @ W[N][K]^T, out f32(+Res) or bf16.
// 128x128 tile, BK=32, 4 waves (2x2), 4x4 16x16x32 frags/wave.
__global__ __launch_bounds__(256) void gemm_bf16_bt(
        const ushort* __restrict__ A, int lda,
        const ushort* __restrict__ W, int ldw,
        const float* __restrict__ Res,
        float* __restrict__ C, ushort* __restrict__ Cbf,
        int ldc, int K) {
    __shared__ ushort As[128 * 32];
    __shared__ ushort Bs[128 * 32];
    int t = threadIdx.x;
    int m0 = blockIdx.y * 128, n0 = blockIdx.x * 128;
    int srow = t >> 2;
    int scol = (t & 3) * 8;
    int lane = t & 63;
    int wid  = t >> 6;
    int wr = wid >> 1, wc = wid & 1;
    int fr = lane & 15;
    int fq = lane >> 4;

    const ushort* Ap = A + (size_t)(m0 + srow) * lda + scol;
    const ushort* Wp = W + (size_t)(n0 + srow) * ldw + scol;
    int sdst = srow * 32 + scol;

    int aoff[4], boff[4];
#pragma unroll
    for (int m = 0; m < 4; m++) aoff[m] = (wr * 64 + m * 16 + fr) * 32 + fq * 8;
#pragma unroll
    for (int n = 0; n < 4; n++) boff[n] = (wc * 64 + n * 16 + fr) * 32 + fq * 8;

    f32x4 acc[4][4];
#pragma unroll
    for (int m = 0; m < 4; m++)
#pragma unroll
        for (int n = 0; n < 4; n++)
#pragma unroll
            for (int r = 0; r < 4; r++) acc[m][n][r] = 0.f;

    for (int k0 = 0; k0 < K; k0 += 32) {
        uint4 a0 = *reinterpret_cast<const uint4*>(Ap + k0);
        uint4 a1 = *reinterpret_cast<const uint4*>(Ap + (size_t)64 * lda + k0);
        uint4 b0 = *reinterpret_cast<const uint4*>(Wp + k0);
        uint4 b1 = *reinterpret_cast<const uint4*>(Wp + (size_t)64 * ldw + k0);
        __syncthreads();
        *reinterpret_cast<uint4*>(&As[sdst])            = a0;
        *reinterpret_cast<uint4*>(&As[sdst + 64 * 32])  = a1;
        *reinterpret_cast<uint4*>(&Bs[sdst])            = b0;
        *reinterpret_cast<uint4*>(&Bs[sdst + 64 * 32])  = b1;
        __syncthreads();
        bf16x8 af[4], bfr[4];
#pragma unroll
        for (int m = 0; m < 4; m++) af[m] = *reinterpret_cast<const bf16x8*>(&As[aoff[m]]);
#pragma unroll
        for (int n = 0; n < 4; n++) bfr[n] = *reinterpret_cast<const bf16x8*>(&Bs[boff[n]]);
#pragma unroll
        for (int m = 0; m < 4; m++)
#pragma unroll
            for (int n = 0; n < 4; n++)
                acc[m][n] = __builtin_amdgcn_mfma_f32_16x16x32_bf16(af[m], bfr[n], acc[m][n], 0, 0, 0);
    }

#pragma unroll
    for (int m = 0; m < 4; m++) {
#pragma unroll
        for (int n = 0; n < 4; n++) {
            int col = n0 + wc * 64 + n * 16 + fr;
#pragma unroll
            for (int r = 0; r < 4; r++) {
                int row = m0 + wr * 64 + m * 16 + fq * 4 + r;
                float v = acc[m][n][r];
                if (Cbf) {
                    Cbf[(size_t)row * ldc + col] = f2bf(v);
                } else {
                    if (Res) v += Res[(size_t)row * ldc + col];
                    C[(size_t)row * ldc + col] = v;
                }
            }
        }
    }
}

// ---------------- skinny x_proj GEMM: part[ks] += Xc[4096x1536] @ Wx[80x1536]^T (K-chunk ks)
// grid (XP_SPLITK, NROWS/64), 4 waves; wave = 16 rows x 80 cols, frags direct from global.
__global__ __launch_bounds__(256) void xproj_gemm(const ushort* __restrict__ Xc,
                                                  const ushort* __restrict__ Wx,
                                                  float* __restrict__ part) {
    int ks = blockIdx.x;
    int m0 = blockIdx.y * 64;
    int wid = threadIdx.x >> 6;
    int lane = threadIdx.x & 63;
    int fr = lane & 15, fq = lane >> 4;
    const ushort* Ap = Xc + (size_t)(m0 + wid * 16 + fr) * DINNER + fq * 8 + ks * XPK;
    const ushort* Wp = Wx + (size_t)fr * DINNER + fq * 8 + ks * XPK;
    f32x4 acc[5];
#pragma unroll
    for (int ct = 0; ct < 5; ct++)
#pragma unroll
        for (int r = 0; r < 4; r++) acc[ct][r] = 0.f;
    for (int k = 0; k < XPK; k += 32) {
        bf16x8 a = *reinterpret_cast<const bf16x8*>(Ap + k);
#pragma unroll
        for (int ct = 0; ct < 5; ct++) {
            bf16x8 b = *reinterpret_cast<const bf16x8*>(Wp + (size_t)ct * 16 * DINNER + k);
            acc[ct] = __builtin_amdgcn_mfma_f32_16x16x32_bf16(a, b, acc[ct], 0, 0, 0);
        }
    }
    float* pbase = part + (size_t)ks * (NROWS * 80);
#pragma unroll
    for (int ct = 0; ct < 5; ct++)
#pragma unroll
        for (int r = 0; r < 4; r++)
            pbase[(size_t)(m0 + wid * 16 + fq * 4 + r) * 80 + ct * 16 + fr] = acc[ct][r];
}

// reduce split-K partials: xdbl = sum_s part[s]
__global__ __launch_bounds__(256) void xproj_reduce(const float* __restrict__ part,
                                                    float* __restrict__ xdbl) {
    int i = blockIdx.x * 256 + threadIdx.x;   // < 327680/4
    const float4* p4 = reinterpret_cast<const float4*>(part);
    float4 s = p4[i];
#pragma unroll
    for (int k = 1; k < XP_SPLITK; k++) {
        float4 v = p4[i + (size_t)k * (NROWS * 80 / 4)];
        s.x += v.x; s.y += v.y; s.z += v.z; s.w += v.w;
    }
    reinterpret_cast<float4*>(xdbl)[i] = s;
}

// ---------------- Generic tiled fp32 GEMM (dt GEMM): C = A @ W^T
__global__ __launch_bounds__(256) void gemm_bt(const float* __restrict__ A, int lda,
                                               const float* __restrict__ W, int ldw,
                                               const float* __restrict__ Res,
                                               float* __restrict__ C, int ldc,
                                               int M, int N, int K) {
    __shared__ float As[16][68];
    __shared__ float Ws[16][68];
    int tid = threadIdx.x;
    int tx = tid & 15, ty = tid >> 4;
    int m0 = blockIdx.y * 64, n0 = blockIdx.x * 64;
    int lrow = tid >> 2;
    int lk   = (tid & 3) * 4;
    int arow = m0 + lrow;
    int wrow = n0 + lrow;
    bool wvalid = (wrow < N);
    float acc[4][4] = {};

    for (int k0 = 0; k0 < K; k0 += 16) {
        float4 av = *reinterpret_cast<const float4*>(A + (size_t)arow * lda + k0 + lk);
        float4 wv = wvalid ? *reinterpret_cast<const float4*>(W + (size_t)wrow * ldw + k0 + lk)
                           : make_float4(0.f, 0.f, 0.f, 0.f);
        __syncthreads();
        As[lk+0][lrow] = av.x; As[lk+1][lrow] = av.y; As[lk+2][lrow] = av.z; As[lk+3][lrow] = av.w;
        Ws[lk+0][lrow] = wv.x; Ws[lk+1][lrow] = wv.y; Ws[lk+2][lrow] = wv.z; Ws[lk+3][lrow] = wv.w;
        __syncthreads();
#pragma unroll
        for (int kk = 0; kk < 16; kk++) {
            float4 a = *reinterpret_cast<const float4*>(&As[kk][ty * 4]);
            float4 w = *reinterpret_cast<const float4*>(&Ws[kk][tx * 4]);
            acc[0][0] += a.x * w.x; acc[0][1] += a.x * w.y; acc[0][2] += a.x * w.z; acc[0][3] += a.x * w.w;
            acc[1][0] += a.y * w.x; acc[1][1] += a.y * w.y; acc[1][2] += a.y * w.z; acc[1][3] += a.y * w.w;
            acc[2][0] += a.z * w.x; acc[2][1] += a.z * w.y; acc[2][2] += a.z * w.z; acc[2][3] += a.z * w.w;
            acc[3][0] += a.w * w.x; acc[3][1] += a.w * w.y; acc[3][2] += a.w * w.z; acc[3][3] += a.w * w.w;
        }
    }

#pragma unroll
    for (int i = 0; i < 4; i++) {
        int row = m0 + ty * 4 + i;
        int col = n0 + tx * 4;
        if (col < N) {
            float4 o = make_float4(acc[i][0], acc[i][1], acc[i][2], acc[i][3]);
            if (Res) {
                float4 r = *reinterpret_cast<const float4*>(Res + (size_t)row * ldc + col);
                o.x += r.x; o.y += r.y; o.z += r.z; o.w += r.w;
            }
            *reinterpret_cast<float4*>(C + (size_t)row * ldc + col) = o;
        }
    }
}

// ---------------- causal depthwise conv (k=4) + bias + SiLU, bf16 in/out, x8
__global__ __launch_bounds__(256) void conv_silu_kernel(const ushort* __restrict__ xz,
                                                        const float* __restrict__ cw,
                                                        const float* __restrict__ cb,
                                                        ushort* __restrict__ out) {
    int i = blockIdx.x * 256 + threadIdx.x;   // < 4096*192
    int d8 = i % (DINNER / 8);
    int ml = i / (DINNER / 8);
    int l  = ml % LL;
    int d  = d8 * 8;
    ushort8 xv[4];
#pragma unroll
    for (int tap = 0; tap < 4; tap++) {
        int li = l - 3 + tap;
        if (li >= 0) xv[tap] = *reinterpret_cast<const ushort8*>(xz + (size_t)(ml - 3 + tap) * 3072 + d);
        else {
            ushort8 z = {0,0,0,0,0,0,0,0};
            xv[tap] = z;
        }
    }
    const float4* cw4 = reinterpret_cast<const float4*>(cw);
    ushort8 o;
#pragma unroll
    for (int j = 0; j < 8; j++) {
        float4 w = cw4[d + j];
        float acc = cb[d + j] + bf2f(xv[0][j]) * w.x + bf2f(xv[1][j]) * w.y
                  + bf2f(xv[2][j]) * w.z + bf2f(xv[3][j]) * w.w;
        o[j] = f2bf(silu_f(acc));
    }
    *reinterpret_cast<ushort8*>(out + (size_t)ml * DINNER + d) = o;
}

// ---------------- selective scan, chunked 3-pass.
__global__ __launch_bounds__(256) void scan_pass1(
        const float* __restrict__ dt, const ushort* __restrict__ xc,
        const float* __restrict__ xdbl, const float* __restrict__ A_log,
        float* __restrict__ hend, float* __restrict__ ssp) {
    __shared__ float Bs[CLEN][DSTATE];
    int tid = threadIdx.x;
    int dgrp = blockIdx.x % DGRPS;
    int chunk = (blockIdx.x / DGRPS) % NCHUNK;
    int b = blockIdx.x / (DGRPS * NCHUNK);
    int d = dgrp * 256 + tid;
    int rbase = b * LL + chunk * CLEN;
    for (int idx = tid; idx < CLEN * DSTATE; idx += 256) {
        int t = idx >> 4, j = idx & 15;
        Bs[t][j] = xdbl[(size_t)(rbase + t) * 80 + DTRANK + j];
    }
    float a[16];
    const float4* ar = reinterpret_cast<const float4*>(A_log + (size_t)d * 16);
#pragma unroll
    for (int i = 0; i < 4; i++) {
        float4 v = ar[i];
        a[4*i+0] = -__expf(v.x); a[4*i+1] = -__expf(v.y);
        a[4*i+2] = -__expf(v.z); a[4*i+3] = -__expf(v.w);
    }
    __syncthreads();
    float h[16];
#pragma unroll
    for (int n = 0; n < 16; n++) h[n] = 0.f;
    float sum_sp = 0.f;
    for (int t = 0; t < CLEN; t++) {
        int rm = rbase + t;
        float dtv = dt[(size_t)rm * DINNER + d];
        float xv  = bf2f(xc[(size_t)rm * DINNER + d]);
        float sp  = softplus_f(dtv);
        sum_sp += sp;
        float du = dtv * xv;
#pragma unroll
        for (int n = 0; n < 16; n++)
            h[n] = __expf(sp * a[n]) * h[n] + du * Bs[t][n];
    }
    size_t o = (size_t)(b * NCHUNK + chunk) * DINNER + d;
    float4* ho = reinterpret_cast<float4*>(hend + o * 16);
#pragma unroll
    for (int i = 0; i < 4; i++)
        ho[i] = make_float4(h[4*i], h[4*i+1], h[4*i+2], h[4*i+3]);
    ssp[o] = sum_sp;
}

__global__ __launch_bounds__(256) void scan_pass2(
        const float* __restrict__ hend, const float* __restrict__ ssp,
        const float* __restrict__ A_log, float* __restrict__ hini) {
    int g = blockIdx.x * 256 + threadIdx.x;   // < 4*1536*16
    int n = g & 15;
    int d = (g >> 4) % DINNER;
    int b = g / (16 * DINNER);
    float a = -__expf(A_log[(size_t)d * 16 + n]);
    float h = 0.f;
    for (int c = 0; c < NCHUNK; c++) {
        size_t o = (size_t)(b * NCHUNK + c) * DINNER + d;
        hini[o * 16 + n] = h;
        h = __expf(a * ssp[o]) * h + hend[o * 16 + n];
    }
}

// Pass 3: fused epilogue y = (sum_n h*C + x*D) * silu(z) -> bf16
__global__ __launch_bounds__(256) void scan_pass3(
        const float* __restrict__ dt, const ushort* __restrict__ xc,
        const float* __restrict__ xdbl, const float* __restrict__ A_log,
        const float* __restrict__ Dp, const ushort* __restrict__ xz,
        const float* __restrict__ hini, ushort* __restrict__ y) {
    __shared__ float BCs[CLEN][2*DSTATE];
    int tid = threadIdx.x;
    int dgrp = blockIdx.x % DGRPS;
    int chunk = (blockIdx.x / DGRPS) % NCHUNK;
    int b = blockIdx.x / (DGRPS * NCHUNK);
    int d = dgrp * 256 + tid;
    int rbase = b * LL + chunk * CLEN;
    for (int idx = tid; idx < CLEN * 2 * DSTATE; idx += 256) {
        int t = idx >> 5, j = idx & 31;
        BCs[t][j] = xdbl[(size_t)(rbase + t) * 80 + DTRANK + j];
    }
    float a[16];
    const float4* ar = reinterpret_cast<const float4*>(A_log + (size_t)d * 16);
#pragma unroll
    for (int i = 0; i < 4; i++) {
        float4 v = ar[i];
        a[4*i+0] = -__expf(v.x); a[4*i+1] = -__expf(v.y);
        a[4*i+2] = -__expf(v.z); a[4*i+3] = -__expf(v.w);
    }
    float dD = Dp[d];
    float h[16];
    size_t o = (size_t)(b * NCHUNK + chunk) * DINNER + d;
    const float4* hi = reinterpret_cast<const float4*>(hini + o * 16);
#pragma unroll
    for (int i = 0; i < 4; i++) {
        float4 v = hi[i];
        h[4*i] = v.x; h[4*i+1] = v.y; h[4*i+2] = v.z; h[4*i+3] = v.w;
    }
    __syncthreads();
    for (int t = 0; t < CLEN; t++) {
        int rm = rbase + t;
        float dtv = dt[(size_t)rm * DINNER + d];
        float xv  = bf2f(xc[(size_t)rm * DINNER + d]);
        float zv  = bf2f(xz[(size_t)rm * 3072 + DINNER + d]);
        float sp  = softplus_f(dtv);
        float du  = dtv * xv;
        float acc = 0.f;
#pragma unroll
        for (int n = 0; n < 16; n++) {
            h[n] = __expf(sp * a[n]) * h[n] + du * BCs[t][n];
            acc += h[n] * BCs[t][DSTATE + n];
        }
        y[(size_t)rm * DINNER + d] = f2bf((acc + xv * dD) * silu_f(zv));
    }
}

extern "C" void kernel_launch(void* const* d_in, const int* in_sizes, int n_in,
                              void* d_out, int out_size, void* d_ws, size_t ws_size,
                              hipStream_t stream) {
    const float* hs        = (const float*)d_in[0];
    const float* norm_w    = (const float*)d_in[1];
    const float* in_proj_w = (const float*)d_in[2];
    const float* conv_w    = (const float*)d_in[3];
    const float* conv_b    = (const float*)d_in[4];
    const float* x_proj_w  = (const float*)d_in[5];
    const float* dt_proj_w = (const float*)d_in[6];
    const float* A_log     = (const float*)d_in[7];
    const float* D_param   = (const float*)d_in[8];
    const float* out_proj_w= (const float*)d_in[9];
    float* out = (float*)d_out;

    float* ws = (float*)d_ws;
    // slotA: h_bf (ushort, first half) then hend (f32) — disjoint lifetimes
    ushort* h_bf = (ushort*)ws;
    float*  hend = ws;                                  // 3,145,728 f32
    ushort* xz_bf    = (ushort*)(ws + 3145728);         // 4096*3072 us (6,291,456 f32)
    ushort* xconv_bf = (ushort*)(ws + 9437184);         // 4096*1536 us (3,145,728 f32)
    float* xdbl  = ws + 12582912;                       // 4096*80 f32
    float* xpart = ws + 12910592;                       // 4*4096*80 f32
    float* dtb   = ws + 14221312;                       // 4096*1536 f32
    ushort* y_bf = (ushort*)(ws + 20512768);            // 4096*1536 us
    float* hini  = ws + 23658496;                       // 3,145,728 f32
    float* ssp   = ws + 26804224;                       // 196,608 f32
    ushort* w_in_bf  = (ushort*)(ws + 27000832);        // 3072*768 us
    ushort* w_out_bf = (ushort*)(ws + 28180480);        // 768*1536 us
    ushort* w_x_bf   = (ushort*)(ws + 28770304);        // 80*1536 us
    // total 28,831,744 f32 ~= 115 MB

    // weight conversions
    f32_to_bf16_x8<<<(294912 + 255)/256, 256, 0, stream>>>(in_proj_w, w_in_bf, 294912);
    f32_to_bf16_x8<<<(147456 + 255)/256, 256, 0, stream>>>(out_proj_w, w_out_bf, 147456);
    f32_to_bf16_x8<<<(15360 + 255)/256, 256, 0, stream>>>(x_proj_w, w_x_bf, 15360);

    rmsnorm_kernel<<<NROWS / 4, 256, 0, stream>>>(hs, norm_w, h_bf);
    // xz = h @ in_proj_w.T  (4096 x 3072, K=768) — bf16 out
    gemm_bf16_bt<<<dim3(3072/128, NROWS/128), 256, 0, stream>>>(
        h_bf, DMODEL, w_in_bf, DMODEL, nullptr, nullptr, xz_bf, 2 * DINNER, DMODEL);
    // causal dwconv + silu on x half (bf16 -> bf16)
    conv_silu_kernel<<<(NROWS * DINNER / 8) / 256, 256, 0, stream>>>(
        xz_bf, conv_w, conv_b, xconv_bf);
    // x_dbl = xconv @ x_proj_w.T  (4096 x 80, K=1536) — skinny MFMA, split-K + reduce
    xproj_gemm<<<dim3(XP_SPLITK, NROWS/64), 256, 0, stream>>>(xconv_bf, w_x_bf, xpart);
    xproj_reduce<<<(NROWS * 80 / 4) / 256, 256, 0, stream>>>(xpart, xdbl);
    // dt = x_dbl[:, :48] @ dt_proj_w.T  (4096 x 1536, K=48) — fp32
    gemm_bt<<<dim3(DINNER / 64, NROWS / 64), 256, 0, stream>>>(
        xdbl, 80, dt_proj_w, DTRANK, nullptr, dtb, DINNER, NROWS, DINNER, DTRANK);
    // chunked selective scan
    scan_pass1<<<BB * NCHUNK * DGRPS, 256, 0, stream>>>(dtb, xconv_bf, xdbl, A_log, hend, ssp);
    scan_pass2<<<(BB * DINNER * DSTATE) / 256, 256, 0, stream>>>(hend, ssp, A_log, hini);
    scan_pass3<<<BB * NCHUNK * DGRPS, 256, 0, stream>>>(dtb, xconv_bf, xdbl, A_log, D_param,
                                                        xz_bf, hini, y_bf);
    // out = residual + y @ out_proj_w.T  (4096 x 768, K=1536) — f32 out + residual
    gemm_bf16_bt<<<dim3(DMODEL/128, NROWS/128), 256, 0, stream>>>(
        y_bf, DINNER, w_out_bf, DINNER, hs, out, nullptr, DMODEL, DINNER);
}

// Round 5
// 278.432 us; speedup vs baseline: 6.2323x; 1.0895x over previous
//
#include <hip/hip_runtime.h>
#include <hip/hip_bf16.h>
#include <math.h>

// Mamba block fwd. bf16-MFMA GEMMs (in/out/x_proj, global_load_lds staging, split-K out_proj)
// + fp32 dt GEMM + chunked 3-pass scan.
// B=4, L=1024, d_model=768, d_inner=1536, dt_rank=48, d_state=16, d_conv=4.

#define BB 4
#define LL 1024
#define DMODEL 768
#define DSTATE 16
#define DINNER 1536
#define DTRANK 48
#define NROWS (BB*LL)   // 4096
#define EPSF 1e-5f
#define NCHUNK 32
#define CLEN 32
#define DGRPS (DINNER/256)   // 6
#define XP_SPLITK 4
#define XPK (DINNER/XP_SPLITK)   // 384
#define OP_SPLITK 4
#define OPK (DINNER/OP_SPLITK)   // 384

typedef __attribute__((ext_vector_type(8))) short bf16x8;
typedef __attribute__((ext_vector_type(8))) ushort ushort8;
typedef __attribute__((ext_vector_type(4))) float f32x4;

__device__ __forceinline__ float softplus_f(float x) {
    return (x > 20.f) ? x : __logf(1.f + __expf(x));
}
__device__ __forceinline__ float silu_f(float x) {
    return x / (1.f + __expf(-x));
}
__device__ __forceinline__ ushort f2bf(float x) {
    union { float f; uint32_t u; } v; v.f = x;
    uint32_t r = v.u + 0x7FFF + ((v.u >> 16) & 1);   // round-to-nearest-even
    return (ushort)(r >> 16);
}
__device__ __forceinline__ float bf2f(ushort u) {
    union { uint32_t u; float f; } v; v.u = ((uint32_t)u) << 16;
    return v.f;
}
// async global->LDS, 16B per lane; LDS dest must be wave-uniform base (+lane*16 by HW)
__device__ __forceinline__ void gload16(const ushort* g, ushort* l) {
    __builtin_amdgcn_global_load_lds(
        (const __attribute__((address_space(1))) unsigned int*)g,
        (__attribute__((address_space(3))) unsigned int*)l, 16, 0, 0);
}

// ---------------- fp32 -> bf16, x8 vectorized (n8 = n/8)
__global__ __launch_bounds__(256) void f32_to_bf16_x8(const float* __restrict__ in,
                                                      ushort* __restrict__ out, int n8) {
    int i = blockIdx.x * 256 + threadIdx.x;
    if (i >= n8) return;
    const float4* ip = reinterpret_cast<const float4*>(in) + (size_t)i * 2;
    float4 v0 = ip[0], v1 = ip[1];
    uint4 o;
    o.x = (uint32_t)f2bf(v0.x) | ((uint32_t)f2bf(v0.y) << 16);
    o.y = (uint32_t)f2bf(v0.z) | ((uint32_t)f2bf(v0.w) << 16);
    o.z = (uint32_t)f2bf(v1.x) | ((uint32_t)f2bf(v1.y) << 16);
    o.w = (uint32_t)f2bf(v1.z) | ((uint32_t)f2bf(v1.w) << 16);
    reinterpret_cast<uint4*>(out)[i] = o;
}

// ---------------- RMSNorm: one wave per row; writes bf16
__global__ __launch_bounds__(256) void rmsnorm_kernel(const float* __restrict__ x,
                                                      const float* __restrict__ w,
                                                      ushort* __restrict__ out) {
    int wave = threadIdx.x >> 6;
    int lane = threadIdx.x & 63;
    int row  = blockIdx.x * 4 + wave;
    const float4* xr = reinterpret_cast<const float4*>(x + (size_t)row * DMODEL);
    const float4* wr = reinterpret_cast<const float4*>(w);
    float4 v[3];
    float ss = 0.f;
#pragma unroll
    for (int i = 0; i < 3; i++) {
        v[i] = xr[lane + i * 64];
        ss += v[i].x*v[i].x + v[i].y*v[i].y + v[i].z*v[i].z + v[i].w*v[i].w;
    }
#pragma unroll
    for (int m = 1; m < 64; m <<= 1) ss += __shfl_xor(ss, m);
    float scale = rsqrtf(ss * (1.0f / DMODEL) + EPSF);
    ushort4* orow = reinterpret_cast<ushort4*>(out + (size_t)row * DMODEL);
#pragma unroll
    for (int i = 0; i < 3; i++) {
        float4 wv = wr[lane + i * 64];
        ushort4 o;
        o.x = f2bf(v[i].x * scale * wv.x);
        o.y = f2bf(v[i].y * scale * wv.y);
        o.z = f2bf(v[i].z * scale * wv.z);
        o.w = f2bf(v[i].w * scale * wv.w);
        orow[lane + i * 64] = o;
    }
}

// ---------------- bf16 MFMA GEMM: Cbf[M][N] = A[M][K] @ W[N][K]^T, bf16 out.
// 128x128 tile, BK=32, 4 waves (2x2), 4x4 16x16x32 frags/wave, global_load_lds staging.
__global__ __launch_bounds__(256) void gemm_bf16_bt(
        const ushort* __restrict__ A, int lda,
        const ushort* __restrict__ W, int ldw,
        ushort* __restrict__ Cbf, int ldc, int K) {
    __shared__ ushort As[128 * 32];
    __shared__ ushort Bs[128 * 32];
    int t = threadIdx.x;
    int m0 = blockIdx.y * 128, n0 = blockIdx.x * 128;
    int srow = t >> 2;
    int scol = (t & 3) * 8;
    int lane = t & 63;
    int wid  = t >> 6;
    int wr = wid >> 1, wc = wid & 1;
    int fr = lane & 15;
    int fq = lane >> 4;

    const ushort* Ap = A + (size_t)(m0 + srow) * lda + scol;
    const ushort* Wp = W + (size_t)(n0 + srow) * ldw + scol;

    int aoff[4], boff[4];
#pragma unroll
    for (int m = 0; m < 4; m++) aoff[m] = (wr * 64 + m * 16 + fr) * 32 + fq * 8;
#pragma unroll
    for (int n = 0; n < 4; n++) boff[n] = (wc * 64 + n * 16 + fr) * 32 + fq * 8;

    f32x4 acc[4][4];
#pragma unroll
    for (int m = 0; m < 4; m++)
#pragma unroll
        for (int n = 0; n < 4; n++)
#pragma unroll
            for (int r = 0; r < 4; r++) acc[m][n][r] = 0.f;

    for (int k0 = 0; k0 < K; k0 += 32) {
        __syncthreads();
        gload16(Ap + k0,                    &As[wid * 512]);
        gload16(Ap + (size_t)64 * lda + k0, &As[2048 + wid * 512]);
        gload16(Wp + k0,                    &Bs[wid * 512]);
        gload16(Wp + (size_t)64 * ldw + k0, &Bs[2048 + wid * 512]);
        __syncthreads();
        bf16x8 af[4], bfr[4];
#pragma unroll
        for (int m = 0; m < 4; m++) af[m] = *reinterpret_cast<const bf16x8*>(&As[aoff[m]]);
#pragma unroll
        for (int n = 0; n < 4; n++) bfr[n] = *reinterpret_cast<const bf16x8*>(&Bs[boff[n]]);
#pragma unroll
        for (int m = 0; m < 4; m++)
#pragma unroll
            for (int n = 0; n < 4; n++)
                acc[m][n] = __builtin_amdgcn_mfma_f32_16x16x32_bf16(af[m], bfr[n], acc[m][n], 0, 0, 0);
    }

#pragma unroll
    for (int m = 0; m < 4; m++) {
#pragma unroll
        for (int n = 0; n < 4; n++) {
            int col = n0 + wc * 64 + n * 16 + fr;
#pragma unroll
            for (int r = 0; r < 4; r++) {
                int row = m0 + wr * 64 + m * 16 + fq * 4 + r;
                Cbf[(size_t)row * ldc + col] = f2bf(acc[m][n][r]);
            }
        }
    }
}

// ---------------- split-K bf16 MFMA GEMM: part[z] = A @ W^T over K-range z. f32 partials.
__global__ __launch_bounds__(256) void gemm_bf16_splitk(
        const ushort* __restrict__ A, int lda,
        const ushort* __restrict__ W, int ldw,
        float* __restrict__ part, int N, int Kc) {
    __shared__ ushort As[128 * 32];
    __shared__ ushort Bs[128 * 32];
    int t = threadIdx.x;
    int m0 = blockIdx.y * 128, n0 = blockIdx.x * 128;
    int kbase = blockIdx.z * Kc;
    int srow = t >> 2;
    int scol = (t & 3) * 8;
    int lane = t & 63;
    int wid  = t >> 6;
    int wr = wid >> 1, wc = wid & 1;
    int fr = lane & 15;
    int fq = lane >> 4;

    const ushort* Ap = A + (size_t)(m0 + srow) * lda + kbase + scol;
    const ushort* Wp = W + (size_t)(n0 + srow) * ldw + kbase + scol;

    int aoff[4], boff[4];
#pragma unroll
    for (int m = 0; m < 4; m++) aoff[m] = (wr * 64 + m * 16 + fr) * 32 + fq * 8;
#pragma unroll
    for (int n = 0; n < 4; n++) boff[n] = (wc * 64 + n * 16 + fr) * 32 + fq * 8;

    f32x4 acc[4][4];
#pragma unroll
    for (int m = 0; m < 4; m++)
#pragma unroll
        for (int n = 0; n < 4; n++)
#pragma unroll
            for (int r = 0; r < 4; r++) acc[m][n][r] = 0.f;

    for (int k0 = 0; k0 < Kc; k0 += 32) {
        __syncthreads();
        gload16(Ap + k0,                    &As[wid * 512]);
        gload16(Ap + (size_t)64 * lda + k0, &As[2048 + wid * 512]);
        gload16(Wp + k0,                    &Bs[wid * 512]);
        gload16(Wp + (size_t)64 * ldw + k0, &Bs[2048 + wid * 512]);
        __syncthreads();
        bf16x8 af[4], bfr[4];
#pragma unroll
        for (int m = 0; m < 4; m++) af[m] = *reinterpret_cast<const bf16x8*>(&As[aoff[m]]);
#pragma unroll
        for (int n = 0; n < 4; n++) bfr[n] = *reinterpret_cast<const bf16x8*>(&Bs[boff[n]]);
#pragma unroll
        for (int m = 0; m < 4; m++)
#pragma unroll
            for (int n = 0; n < 4; n++)
                acc[m][n] = __builtin_amdgcn_mfma_f32_16x16x32_bf16(af[m], bfr[n], acc[m][n], 0, 0, 0);
    }

    float* pb = part + (size_t)blockIdx.z * NROWS * N;
#pragma unroll
    for (int m = 0; m < 4; m++) {
#pragma unroll
        for (int n = 0; n < 4; n++) {
            int col = n0 + wc * 64 + n * 16 + fr;
#pragma unroll
            for (int r = 0; r < 4; r++) {
                int row = m0 + wr * 64 + m * 16 + fq * 4 + r;
                pb[(size_t)row * N + col] = acc[m][n][r];
            }
        }
    }
}

// out = residual + sum_z part[z], float4
__global__ __launch_bounds__(256) void reduce4_res(const float* __restrict__ part,
                                                   const float* __restrict__ res,
                                                   float* __restrict__ out) {
    int i = blockIdx.x * 256 + threadIdx.x;   // < NROWS*DMODEL/4
    const float4* p4 = reinterpret_cast<const float4*>(part);
    float4 s = reinterpret_cast<const float4*>(res)[i];
#pragma unroll
    for (int z = 0; z < OP_SPLITK; z++) {
        float4 v = p4[i + (size_t)z * (NROWS * DMODEL / 4)];
        s.x += v.x; s.y += v.y; s.z += v.z; s.w += v.w;
    }
    reinterpret_cast<float4*>(out)[i] = s;
}

// ---------------- skinny x_proj GEMM: part[ks] = Xc @ Wx^T (K-chunk ks), frags from global
__global__ __launch_bounds__(256) void xproj_gemm(const ushort* __restrict__ Xc,
                                                  const ushort* __restrict__ Wx,
                                                  float* __restrict__ part) {
    int ks = blockIdx.x;
    int m0 = blockIdx.y * 64;
    int wid = threadIdx.x >> 6;
    int lane = threadIdx.x & 63;
    int fr = lane & 15, fq = lane >> 4;
    const ushort* Ap = Xc + (size_t)(m0 + wid * 16 + fr) * DINNER + fq * 8 + ks * XPK;
    const ushort* Wp = Wx + (size_t)fr * DINNER + fq * 8 + ks * XPK;
    f32x4 acc[5];
#pragma unroll
    for (int ct = 0; ct < 5; ct++)
#pragma unroll
        for (int r = 0; r < 4; r++) acc[ct][r] = 0.f;
    for (int k = 0; k < XPK; k += 32) {
        bf16x8 a = *reinterpret_cast<const bf16x8*>(Ap + k);
#pragma unroll
        for (int ct = 0; ct < 5; ct++) {
            bf16x8 b = *reinterpret_cast<const bf16x8*>(Wp + (size_t)ct * 16 * DINNER + k);
            acc[ct] = __builtin_amdgcn_mfma_f32_16x16x32_bf16(a, b, acc[ct], 0, 0, 0);
        }
    }
    float* pbase = part + (size_t)ks * (NROWS * 80);
#pragma unroll
    for (int ct = 0; ct < 5; ct++)
#pragma unroll
        for (int r = 0; r < 4; r++)
            pbase[(size_t)(m0 + wid * 16 + fq * 4 + r) * 80 + ct * 16 + fr] = acc[ct][r];
}

// reduce split-K partials: xdbl = sum_s part[s]
__global__ __launch_bounds__(256) void xproj_reduce(const float* __restrict__ part,
                                                    float* __restrict__ xdbl) {
    int i = blockIdx.x * 256 + threadIdx.x;   // < 327680/4
    const float4* p4 = reinterpret_cast<const float4*>(part);
    float4 s = p4[i];
#pragma unroll
    for (int k = 1; k < XP_SPLITK; k++) {
        float4 v = p4[i + (size_t)k * (NROWS * 80 / 4)];
        s.x += v.x; s.y += v.y; s.z += v.z; s.w += v.w;
    }
    reinterpret_cast<float4*>(xdbl)[i] = s;
}

// ---------------- Generic tiled fp32 GEMM (dt GEMM): C = A @ W^T
__global__ __launch_bounds__(256) void gemm_bt(const float* __restrict__ A, int lda,
                                               const float* __restrict__ W, int ldw,
                                               float* __restrict__ C, int ldc,
                                               int M, int N, int K) {
    __shared__ float As[16][68];
    __shared__ float Ws[16][68];
    int tid = threadIdx.x;
    int tx = tid & 15, ty = tid >> 4;
    int m0 = blockIdx.y * 64, n0 = blockIdx.x * 64;
    int lrow = tid >> 2;
    int lk   = (tid & 3) * 4;
    int arow = m0 + lrow;
    int wrow = n0 + lrow;
    bool wvalid = (wrow < N);
    float acc[4][4] = {};

    for (int k0 = 0; k0 < K; k0 += 16) {
        float4 av = *reinterpret_cast<const float4*>(A + (size_t)arow * lda + k0 + lk);
        float4 wv = wvalid ? *reinterpret_cast<const float4*>(W + (size_t)wrow * ldw + k0 + lk)
                           : make_float4(0.f, 0.f, 0.f, 0.f);
        __syncthreads();
        As[lk+0][lrow] = av.x; As[lk+1][lrow] = av.y; As[lk+2][lrow] = av.z; As[lk+3][lrow] = av.w;
        Ws[lk+0][lrow] = wv.x; Ws[lk+1][lrow] = wv.y; Ws[lk+2][lrow] = wv.z; Ws[lk+3][lrow] = wv.w;
        __syncthreads();
#pragma unroll
        for (int kk = 0; kk < 16; kk++) {
            float4 a = *reinterpret_cast<const float4*>(&As[kk][ty * 4]);
            float4 w = *reinterpret_cast<const float4*>(&Ws[kk][tx * 4]);
            acc[0][0] += a.x * w.x; acc[0][1] += a.x * w.y; acc[0][2] += a.x * w.z; acc[0][3] += a.x * w.w;
            acc[1][0] += a.y * w.x; acc[1][1] += a.y * w.y; acc[1][2] += a.y * w.z; acc[1][3] += a.y * w.w;
            acc[2][0] += a.z * w.x; acc[2][1] += a.z * w.y; acc[2][2] += a.z * w.z; acc[2][3] += a.z * w.w;
            acc[3][0] += a.w * w.x; acc[3][1] += a.w * w.y; acc[3][2] += a.w * w.z; acc[3][3] += a.w * w.w;
        }
    }

#pragma unroll
    for (int i = 0; i < 4; i++) {
        int row = m0 + ty * 4 + i;
        int col = n0 + tx * 4;
        if (col < N) {
            float4 o = make_float4(acc[i][0], acc[i][1], acc[i][2], acc[i][3]);
            *reinterpret_cast<float4*>(C + (size_t)row * ldc + col) = o;
        }
    }
}

// ---------------- causal depthwise conv (k=4) + bias + SiLU, bf16 in/out, x8
__global__ __launch_bounds__(256) void conv_silu_kernel(const ushort* __restrict__ xz,
                                                        const float* __restrict__ cw,
                                                        const float* __restrict__ cb,
                                                        ushort* __restrict__ out) {
    int i = blockIdx.x * 256 + threadIdx.x;   // < 4096*192
    int d8 = i % (DINNER / 8);
    int ml = i / (DINNER / 8);
    int l  = ml % LL;
    int d  = d8 * 8;
    ushort8 xv[4];
#pragma unroll
    for (int tap = 0; tap < 4; tap++) {
        int li = l - 3 + tap;
        if (li >= 0) xv[tap] = *reinterpret_cast<const ushort8*>(xz + (size_t)(ml - 3 + tap) * 3072 + d);
        else {
            ushort8 z = {0,0,0,0,0,0,0,0};
            xv[tap] = z;
        }
    }
    const float4* cw4 = reinterpret_cast<const float4*>(cw);
    ushort8 o;
#pragma unroll
    for (int j = 0; j < 8; j++) {
        float4 w = cw4[d + j];
        float acc = cb[d + j] + bf2f(xv[0][j]) * w.x + bf2f(xv[1][j]) * w.y
                  + bf2f(xv[2][j]) * w.z + bf2f(xv[3][j]) * w.w;
        o[j] = f2bf(silu_f(acc));
    }
    *reinterpret_cast<ushort8*>(out + (size_t)ml * DINNER + d) = o;
}

// ---------------- selective scan, chunked 3-pass.
__global__ __launch_bounds__(256) void scan_pass1(
        const float* __restrict__ dt, const ushort* __restrict__ xc,
        const float* __restrict__ xdbl, const float* __restrict__ A_log,
        float* __restrict__ hend, float* __restrict__ ssp) {
    __shared__ float Bs[CLEN][DSTATE];
    int tid = threadIdx.x;
    int dgrp = blockIdx.x % DGRPS;
    int chunk = (blockIdx.x / DGRPS) % NCHUNK;
    int b = blockIdx.x / (DGRPS * NCHUNK);
    int d = dgrp * 256 + tid;
    int rbase = b * LL + chunk * CLEN;
    for (int idx = tid; idx < CLEN * DSTATE; idx += 256) {
        int t = idx >> 4, j = idx & 15;
        Bs[t][j] = xdbl[(size_t)(rbase + t) * 80 + DTRANK + j];
    }
    float a[16];
    const float4* ar = reinterpret_cast<const float4*>(A_log + (size_t)d * 16);
#pragma unroll
    for (int i = 0; i < 4; i++) {
        float4 v = ar[i];
        a[4*i+0] = -__expf(v.x); a[4*i+1] = -__expf(v.y);
        a[4*i+2] = -__expf(v.z); a[4*i+3] = -__expf(v.w);
    }
    __syncthreads();
    float h[16];
#pragma unroll
    for (int n = 0; n < 16; n++) h[n] = 0.f;
    float sum_sp = 0.f;
    for (int t = 0; t < CLEN; t++) {
        int rm = rbase + t;
        float dtv = dt[(size_t)rm * DINNER + d];
        float xv  = bf2f(xc[(size_t)rm * DINNER + d]);
        float sp  = softplus_f(dtv);
        sum_sp += sp;
        float du = dtv * xv;
#pragma unroll
        for (int n = 0; n < 16; n++)
            h[n] = __expf(sp * a[n]) * h[n] + du * Bs[t][n];
    }
    size_t o = (size_t)(b * NCHUNK + chunk) * DINNER + d;
    float4* ho = reinterpret_cast<float4*>(hend + o * 16);
#pragma unroll
    for (int i = 0; i < 4; i++)
        ho[i] = make_float4(h[4*i], h[4*i+1], h[4*i+2], h[4*i+3]);
    ssp[o] = sum_sp;
}

__global__ __launch_bounds__(256) void scan_pass2(
        const float* __restrict__ hend, const float* __restrict__ ssp,
        const float* __restrict__ A_log, float* __restrict__ hini) {
    int g = blockIdx.x * 256 + threadIdx.x;   // < 4*1536*16
    int n = g & 15;
    int d = (g >> 4) % DINNER;
    int b = g / (16 * DINNER);
    float a = -__expf(A_log[(size_t)d * 16 + n]);
    float h = 0.f;
    for (int c = 0; c < NCHUNK; c++) {
        size_t o = (size_t)(b * NCHUNK + c) * DINNER + d;
        hini[o * 16 + n] = h;
        h = __expf(a * ssp[o]) * h + hend[o * 16 + n];
    }
}

// Pass 3: fused epilogue y = (sum_n h*C + x*D) * silu(z) -> bf16
__global__ __launch_bounds__(256) void scan_pass3(
        const float* __restrict__ dt, const ushort* __restrict__ xc,
        const float* __restrict__ xdbl, const float* __restrict__ A_log,
        const float* __restrict__ Dp, const ushort* __restrict__ xz,
        const float* __restrict__ hini, ushort* __restrict__ y) {
    __shared__ float BCs[CLEN][2*DSTATE];
    int tid = threadIdx.x;
    int dgrp = blockIdx.x % DGRPS;
    int chunk = (blockIdx.x / DGRPS) % NCHUNK;
    int b = blockIdx.x / (DGRPS * NCHUNK);
    int d = dgrp * 256 + tid;
    int rbase = b * LL + chunk * CLEN;
    for (int idx = tid; idx < CLEN * 2 * DSTATE; idx += 256) {
        int t = idx >> 5, j = idx & 31;
        BCs[t][j] = xdbl[(size_t)(rbase + t) * 80 + DTRANK + j];
    }
    float a[16];
    const float4* ar = reinterpret_cast<const float4*>(A_log + (size_t)d * 16);
#pragma unroll
    for (int i = 0; i < 4; i++) {
        float4 v = ar[i];
        a[4*i+0] = -__expf(v.x); a[4*i+1] = -__expf(v.y);
        a[4*i+2] = -__expf(v.z); a[4*i+3] = -__expf(v.w);
    }
    float dD = Dp[d];
    float h[16];
    size_t o = (size_t)(b * NCHUNK + chunk) * DINNER + d;
    const float4* hi = reinterpret_cast<const float4*>(hini + o * 16);
#pragma unroll
    for (int i = 0; i < 4; i++) {
        float4 v = hi[i];
        h[4*i] = v.x; h[4*i+1] = v.y; h[4*i+2] = v.z; h[4*i+3] = v.w;
    }
    __syncthreads();
    for (int t = 0; t < CLEN; t++) {
        int rm = rbase + t;
        float dtv = dt[(size_t)rm * DINNER + d];
        float xv  = bf2f(xc[(size_t)rm * DINNER + d]);
        float zv  = bf2f(xz[(size_t)rm * 3072 + DINNER + d]);
        float sp  = softplus_f(dtv);
        float du  = dtv * xv;
        float acc = 0.f;
#pragma unroll
        for (int n = 0; n < 16; n++) {
            h[n] = __expf(sp * a[n]) * h[n] + du * BCs[t][n];
            acc += h[n] * BCs[t][DSTATE + n];
        }
        y[(size_t)rm * DINNER + d] = f2bf((acc + xv * dD) * silu_f(zv));
    }
}

extern "C" void kernel_launch(void* const* d_in, const int* in_sizes, int n_in,
                              void* d_out, int out_size, void* d_ws, size_t ws_size,
                              hipStream_t stream) {
    const float* hs        = (const float*)d_in[0];
    const float* norm_w    = (const float*)d_in[1];
    const float* in_proj_w = (const float*)d_in[2];
    const float* conv_w    = (const float*)d_in[3];
    const float* conv_b    = (const float*)d_in[4];
    const float* x_proj_w  = (const float*)d_in[5];
    const float* dt_proj_w = (const float*)d_in[6];
    const float* A_log     = (const float*)d_in[7];
    const float* D_param   = (const float*)d_in[8];
    const float* out_proj_w= (const float*)d_in[9];
    float* out = (float*)d_out;

    float* ws = (float*)d_ws;
    // slotA: h_bf (ushort, first half) then hend (f32) — disjoint lifetimes
    ushort* h_bf = (ushort*)ws;
    float*  hend = ws;                                  // 3,145,728 f32
    ushort* xz_bf    = (ushort*)(ws + 3145728);         // 4096*3072 us (6,291,456 f32)
    ushort* xconv_bf = (ushort*)(ws + 9437184);         // 4096*1536 us (3,145,728 f32)
    float* xdbl  = ws + 12582912;                       // 4096*80 f32
    float* xpart = ws + 12910592;                       // 4*4096*80 f32
    float* dtb   = ws + 14221312;                       // 4096*1536 f32
    ushort* y_bf = (ushort*)(ws + 20512768);            // 4096*1536 us
    float* hini  = ws + 23658496;                       // 3,145,728 f32
    float* ssp   = ws + 26804224;                       // 196,608 f32
    ushort* w_in_bf  = (ushort*)(ws + 27000832);        // 3072*768 us
    ushort* w_out_bf = (ushort*)(ws + 28180480);        // 768*1536 us
    ushort* w_x_bf   = (ushort*)(ws + 28770304);        // 80*1536 us
    // opart (out_proj split-K partials): 4*4096*768 = 12,582,912 f32, aliased onto
    // xz/xconv/xdbl/xpart/dtb slots (all dead after scan_pass3); ends before y_bf.
    float* opart = ws + 3145728;
    // total footprint unchanged: 28,831,744 f32 ~= 115 MB

    // weight conversions
    f32_to_bf16_x8<<<(294912 + 255)/256, 256, 0, stream>>>(in_proj_w, w_in_bf, 294912);
    f32_to_bf16_x8<<<(147456 + 255)/256, 256, 0, stream>>>(out_proj_w, w_out_bf, 147456);
    f32_to_bf16_x8<<<(15360 + 255)/256, 256, 0, stream>>>(x_proj_w, w_x_bf, 15360);

    rmsnorm_kernel<<<NROWS / 4, 256, 0, stream>>>(hs, norm_w, h_bf);
    // xz = h @ in_proj_w.T  (4096 x 3072, K=768) — bf16 out
    gemm_bf16_bt<<<dim3(3072/128, NROWS/128), 256, 0, stream>>>(
        h_bf, DMODEL, w_in_bf, DMODEL, xz_bf, 2 * DINNER, DMODEL);
    // causal dwconv + silu on x half (bf16 -> bf16)
    conv_silu_kernel<<<(NROWS * DINNER / 8) / 256, 256, 0, stream>>>(
        xz_bf, conv_w, conv_b, xconv_bf);
    // x_dbl = xconv @ x_proj_w.T  (4096 x 80, K=1536) — skinny MFMA, split-K + reduce
    xproj_gemm<<<dim3(XP_SPLITK, NROWS/64), 256, 0, stream>>>(xconv_bf, w_x_bf, xpart);
    xproj_reduce<<<(NROWS * 80 / 4) / 256, 256, 0, stream>>>(xpart, xdbl);
    // dt = x_dbl[:, :48] @ dt_proj_w.T  (4096 x 1536, K=48) — fp32
    gemm_bt<<<dim3(DINNER / 64, NROWS / 64), 256, 0, stream>>>(
        xdbl, 80, dt_proj_w, DTRANK, dtb, DINNER, NROWS, DINNER, DTRANK);
    // chunked selective scan
    scan_pass1<<<BB * NCHUNK * DGRPS, 256, 0, stream>>>(dtb, xconv_bf, xdbl, A_log, hend, ssp);
    scan_pass2<<<(BB * DINNER * DSTATE) / 256, 256, 0, stream>>>(hend, ssp, A_log, hini);
    scan_pass3<<<BB * NCHUNK * DGRPS, 256, 0, stream>>>(dtb, xconv_bf, xdbl, A_log, D_param,
                                                        xz_bf, hini, y_bf);
    // out = residual + y @ out_proj_w.T  (4096 x 768, K=1536) — split-K=4 + fused reduce
    gemm_bf16_splitk<<<dim3(DMODEL/128, NROWS/128, OP_SPLITK), 256, 0, stream>>>(
        y_bf, DINNER, w_out_bf, DINNER, opart, DMODEL, OPK);
    reduce4_res<<<(NROWS * DMODEL / 4) / 256, 256, 0, stream>>>(opart, hs, out);
}